// Round 10
// baseline (2307.036 us; speedup 1.0000x reference)
//
#include <hip/hip_runtime.h>
#include <hip/hip_bf16.h>
#include <math.h>

typedef __attribute__((ext_vector_type(8))) short bf16x8;
typedef __attribute__((ext_vector_type(4))) float f32x4;

#define B_ 128
#define N_ 197
#define F_ 768
#define NH_ 512
#define D2_ 1024
#define D4_ 2048
#define NC_ 1000
#define ROWS_ (B_ * N_)   // 25216 = 197 * 128
#define KA_ 224           // agg K padded per batch (197 -> 224), per-batch phase pad b&3
#define NA_ 256           // agg node rows padded
#define LDG_ 200          // gram leading dim (197 -> 200, mult of 4 for f32x4 stores)
#define MT_LD_ (B_ * KA_) // msgT row length: 128*224 = 28672

// workspace offsets (bytes). g0 overlays A2bf (g0 dead after topk). Fet_lo overlays
// msgT+h1 head (lo dead after gram; stale msgT pad bytes are finite bf16, killed by A2 zeros).
#define OFF_G0     0ull           // [25216][200] f32 = 20,172,800
#define OFF_SQ     20172800ull
#define OFF_ABITS  20273664ull    // [25216][4] u64
#define OFF_DEG    21080576ull
#define OFF_FETHI  21181440ull    // [25280][768] bf16
#define OFF_MSGT   60011520ull    // [512][28672] bf16 = 29,360,128
#define OFF_H1     89371648ull    // [25216][1024] bf16
#define OFF_FETLO  OFF_MSGT       // overlay
#define OFF_POOL   141014016ull   // [128][2048] f32
#define OFF_P      142062592ull   // [128][512] f32
#define OFF_WC1    142324736ull   // [1024][768] bf16
#define OFF_WC2    143897600ull   // [1024][1024] bf16
#define OFF_G1     145994752ull   // [25216][200] f32, end 166,167,552

__device__ __forceinline__ void gll16(const void* g, void* l) {
  __builtin_amdgcn_global_load_lds((const __attribute__((address_space(1))) void*)g,
                                   (__attribute__((address_space(3))) void*)l, 16, 0, 0);
}

// Paired-row LDS layout for a 128row x 64B tile stored as [64][128B]:
// logical (row ar, 16B-chunk fch) lives at phys row (ar&63),
// slot ((ar>>6)*4 + fch) ^ ((ar&63)&7). Conflict-free (2-way) ds_read_b128.

// ---------------- all four weight casts in one launch ----------------
__global__ __launch_bounds__(256) void cast_weights(const float* __restrict__ w10,
                                                    const float* __restrict__ w20,
                                                    const float* __restrict__ w11,
                                                    const float* __restrict__ w21,
                                                    __hip_bfloat16* __restrict__ wc1,
                                                    __hip_bfloat16* __restrict__ wc2) {
  const int S1 = NH_ * F_ / 4;   // 98304
  const int S2 = NH_ * D2_ / 4;  // 131072
  int i = blockIdx.x * 256 + threadIdx.x;
  const float* src;
  __hip_bfloat16* dst;
  int off;
  if (i < S1) { src = w10; dst = wc1; off = i; }
  else if (i < 2 * S1) { src = w20; dst = wc1 + (size_t)NH_ * F_; off = i - S1; }
  else if (i < 2 * S1 + S2) { src = w11; dst = wc2; off = i - 2 * S1; }
  else { src = w21; dst = wc2 + (size_t)NH_ * D2_; off = i - 2 * S1 - S2; }
  float4 v = ((const float4*)src)[off];
  union { __hip_bfloat16 h[4]; uint2 u; } pk;
  pk.h[0] = __float2bfloat16(v.x);
  pk.h[1] = __float2bfloat16(v.y);
  pk.h[2] = __float2bfloat16(v.z);
  pk.h[3] = __float2bfloat16(v.w);
  ((uint2*)dst)[off] = pk.u;
}

// ---------------- f32 -> bf16 hi/lo split + squared norms (one Fet read) ----------------
__global__ __launch_bounds__(256) void cast_hilo_sq(const float* __restrict__ X,
                                                    __hip_bfloat16* __restrict__ hi,
                                                    __hip_bfloat16* __restrict__ lo,
                                                    float* __restrict__ sq) {
  int row = blockIdx.x * 4 + (threadIdx.x >> 6);
  int lane = threadIdx.x & 63;
  const float4* xp = (const float4*)(X + (size_t)row * F_);
  uint2* hp = (uint2*)(hi + (size_t)row * F_);
  uint2* lp = (uint2*)(lo + (size_t)row * F_);
  float s = 0.f;
#pragma unroll
  for (int i = 0; i < 3; i++) {
    float4 v = xp[lane + i * 64];
    s += v.x * v.x + v.y * v.y + v.z * v.z + v.w * v.w;
    float f[4] = {v.x, v.y, v.z, v.w};
    union { __hip_bfloat16 h[4]; uint2 u; } ph, pl;
#pragma unroll
    for (int k = 0; k < 4; k++) {
      __hip_bfloat16 h = __float2bfloat16(f[k]);
      ph.h[k] = h;
      pl.h[k] = __float2bfloat16(f[k] - __bfloat162float(h));
    }
    hp[lane + i * 64] = ph.u;
    lp[lane + i * 64] = pl.u;
  }
#pragma unroll
  for (int o = 32; o > 0; o >>= 1) s += __shfl_down(s, o);
  if (lane == 0) sq[row] = s;
}

// ---------------- pairwise Gram via MFMA, split-bf16 3-pass, K-split x2 (BK=32) -------
__global__ __launch_bounds__(256) void mfma_gram(const __hip_bfloat16* __restrict__ Xhi,
                                                 const __hip_bfloat16* __restrict__ Xlo,
                                                 float* __restrict__ g0,
                                                 float* __restrict__ g1) {
  __shared__ short AsH[4096];
  __shared__ short BsH[4096];
  __shared__ short AsL[4096];
  __shared__ short BsL[4096];
  const int t = threadIdx.x;
  const int wgid = blockIdx.x;
  const int L = (wgid & 7) * 96 + (wgid >> 3);
  const int b = L / 6;
  const int rbx = L - b * 6;
  const int bx = rbx % 3;
  const int khalf = rbx / 3;
  const int m0 = (bx == 0) ? 0 : 128;
  const int o0 = (bx == 2) ? 128 : 0;
  const bool mirror = (bx == 1);
  const int l = t & 63, w = t >> 6;
  const int wm = (w >> 1) * 64, wn = (w & 1) * 64;
  const int frow = l & 15, fch = l >> 4;
  const size_t rowbase = (size_t)b * N_;
  const char* AhiB = (const char*)(Xhi + (rowbase + m0) * F_);
  const char* AloB = (const char*)(Xlo + (rowbase + m0) * F_);
  const char* BhiB = (const char*)(Xhi + (rowbase + o0) * F_);
  const char* BloB = (const char*)(Xlo + (rowbase + o0) * F_);
  const int rb = F_ * 2;
  char* AsHB = (char*)AsH;
  char* BsHB = (char*)BsH;
  char* AsLB = (char*)AsL;
  char* BsLB = (char*)BsL;
  float* go = khalf ? g1 : g0;
  f32x4 zero = {0.f, 0.f, 0.f, 0.f};
  f32x4 acc[4][4];
#pragma unroll
  for (int i = 0; i < 4; i++)
#pragma unroll
    for (int j = 0; j < 4; j++) acc[i][j] = zero;
  const int kt0 = khalf * 12;
  for (int kt = kt0; kt < kt0 + 12; kt++) {
    const int kb = kt * 64;
#pragma unroll
    for (int u = 0; u < 2; u++) {
      int prow = u * 32 + (t >> 3);
      int e = (t & 7) ^ (prow & 7);
      int grow = (e >> 2) * 64 + prow;
      size_t goff = (size_t)grow * rb + kb + (e & 3) * 16;
      gll16(AhiB + goff, AsHB + u * 4096 + t * 16);
      gll16(BhiB + goff, BsHB + u * 4096 + t * 16);
      gll16(AloB + goff, AsLB + u * 4096 + t * 16);
      gll16(BloB + goff, BsLB + u * 4096 + t * 16);
    }
    __syncthreads();
    bf16x8 ah[4], al[4], bh[4], bl[4];
#pragma unroll
    for (int i = 0; i < 4; i++) {
      int ar = wm + i * 16 + frow;
      int apr = ar & 63;
      int aoff = apr * 128 + (((((ar >> 6) << 2) | fch) ^ (apr & 7)) * 16);
      ah[i] = *(const bf16x8*)(AsHB + aoff);
      al[i] = *(const bf16x8*)(AsLB + aoff);
      int br = wn + i * 16 + frow;
      int bpr = br & 63;
      int boff = bpr * 128 + (((((br >> 6) << 2) | fch) ^ (bpr & 7)) * 16);
      bh[i] = *(const bf16x8*)(BsHB + boff);
      bl[i] = *(const bf16x8*)(BsLB + boff);
    }
    // swapped: D col = A-tile row (n), D row = B-tile row (m)
#pragma unroll
    for (int i = 0; i < 4; i++)
#pragma unroll
      for (int j = 0; j < 4; j++) {
        acc[i][j] = __builtin_amdgcn_mfma_f32_16x16x32_bf16(bh[j], ah[i], acc[i][j], 0, 0, 0);
        acc[i][j] = __builtin_amdgcn_mfma_f32_16x16x32_bf16(bl[j], ah[i], acc[i][j], 0, 0, 0);
        acc[i][j] = __builtin_amdgcn_mfma_f32_16x16x32_bf16(bh[j], al[i], acc[i][j], 0, 0, 0);
      }
    __syncthreads();
  }
#pragma unroll
  for (int i = 0; i < 4; i++) {
    int n = m0 + wm + i * 16 + frow;
    if (n >= N_) continue;
    float* gr = go + (rowbase + n) * LDG_;
#pragma unroll
    for (int j = 0; j < 4; j++) {
      int mb = o0 + wn + j * 16 + fch * 4;
      if (mb >= LDG_) continue;
      f32x4 pv = acc[i][j];
      *(f32x4*)&gr[mb] = pv;
      if (mirror) {
#pragma unroll
        for (int r = 0; r < 4; r++)
          go[(rowbase + mb + r) * LDG_ + n] = pv[r];
      }
    }
  }
}

// ---------------- top-4 per row -> symmetric adjacency bitmask ----------------
__global__ __launch_bounds__(256) void topk_kernel(const float* __restrict__ g0,
                                                   const float* __restrict__ g1,
                                                   const float* __restrict__ sq,
                                                   unsigned long long* __restrict__ Abits) {
  int row = blockIdx.x * 4 + (threadIdx.x >> 6);
  int lane = threadIdx.x & 63;
  int b = row / N_, n = row - b * N_;
  const float* g0r = g0 + (size_t)row * LDG_;
  const float* g1r = g1 + (size_t)row * LDG_;
  const float* sqb = sq + (size_t)b * N_;
  float v[4];
  int vi[4];
#pragma unroll
  for (int i = 0; i < 4; i++) {
    int m = lane + i * 64;
    bool ok = (m < N_) && (m != n);
    v[i] = ok ? (sqb[m] - 2.f * (g0r[m] + g1r[m])) : INFINITY;
    vi[i] = ok ? m : 0x3fffffff;
  }
  unsigned long long nbr[4] = {0ull, 0ull, 0ull, 0ull};
#pragma unroll
  for (int t = 0; t < 4; t++) {
    float bv = v[0];
    int bi = vi[0];
#pragma unroll
    for (int i = 1; i < 4; i++)
      if (v[i] < bv || (v[i] == bv && vi[i] < bi)) { bv = v[i]; bi = vi[i]; }
#pragma unroll
    for (int o = 1; o < 64; o <<= 1) {
      float ov = __shfl_xor(bv, o);
      int oi = __shfl_xor(bi, o);
      if (ov < bv || (ov == bv && oi < bi)) { bv = ov; bi = oi; }
    }
#pragma unroll
    for (int i = 0; i < 4; i++)
      if (vi[i] == bi) { v[i] = INFINITY; vi[i] = 0x3fffffff; }
    if (lane == 0) {
      nbr[bi >> 6] |= 1ull << (bi & 63);
      atomicOr(&Abits[((size_t)b * N_ + bi) * 4 + (n >> 6)], 1ull << (n & 63));
    }
  }
  if (lane == 0) {
#pragma unroll
    for (int w = 0; w < 4; w++)
      if (nbr[w]) atomicOr(&Abits[(size_t)row * 4 + w], nbr[w]);
  }
}

// ---------------- 2-hop adjacency -> bf16 [B][256][224] (phase-shift b&3) + deg -------
__global__ __launch_bounds__(256) void a2_kernel(const unsigned long long* __restrict__ Abits,
                                                 __hip_bfloat16* __restrict__ A2bf,
                                                 float* __restrict__ deg) {
  int row = blockIdx.x * 4 + (threadIdx.x >> 6);
  int lane = threadIdx.x & 63;
  int b = row / N_, n = row - b * N_;
  const unsigned long long* arow = Abits + (size_t)row * 4;
  const unsigned long long* base = Abits + (size_t)b * N_ * 4;
  unsigned long long r0 = 0, r1 = 0, r2 = 0, r3 = 0;
#pragma unroll
  for (int w = 0; w < 4; w++) {
    if ((arow[w] >> lane) & 1ull) {
      const unsigned long long* mr = base + (size_t)(w * 64 + lane) * 4;
      r0 |= mr[0]; r1 |= mr[1]; r2 |= mr[2]; r3 |= mr[3];
    }
  }
#pragma unroll
  for (int o = 1; o < 64; o <<= 1) {
    r0 |= __shfl_xor(r0, o);
    r1 |= __shfl_xor(r1, o);
    r2 |= __shfl_xor(r2, o);
    r3 |= __shfl_xor(r3, o);
  }
  unsigned long long rr[4] = {r0, r1, r2, r3};
  rr[n >> 6] &= ~(1ull << (n & 63));
  const int pad = b & 3;
  __hip_bfloat16* out = A2bf + ((size_t)b * NA_ + n) * KA_;
  const __hip_bfloat16 one = __float2bfloat16(1.f);
  const __hip_bfloat16 zer = __float2bfloat16(0.f);
#pragma unroll
  for (int i = 0; i < 4; i++) {
    int m = lane + i * 64;
    if (m < KA_) {
      int k = m - pad;
      bool bit = (k >= 0 && k < N_ && ((rr[k >> 6] >> (k & 63)) & 1ull));
      out[m] = bit ? one : zer;
    }
  }
  if (lane == 0) {
    int dg = __popcll(rr[0]) + __popcll(rr[1]) + __popcll(rr[2]) + __popcll(rr[3]);
    deg[row] = (float)(dg > 0 ? dg : 1);
  }
}

// ---------------- merged ego+msg GEMM over concat weights [1024][K], BK=32 ------------
// __launch_bounds__(256, 6): cap VGPR ~85 so 6 blocks/CU -> 1536 resident, single-round
// grid (1576 blocks). At 5/CU the grid ran 1.23 rounds (23% tail at ~1/5 utilization).
template <int MODE>
__global__ __launch_bounds__(256, 6) void mfma_fused(const __hip_bfloat16* __restrict__ X,
                                                     const __hip_bfloat16* __restrict__ Wcat,
                                                     const float* __restrict__ biasE,
                                                     const float* __restrict__ biasM,
                                                     __hip_bfloat16* __restrict__ h1,
                                                     __hip_bfloat16* __restrict__ msgT,
                                                     float* __restrict__ pool,
                                                     int K) {
  __shared__ short As[4096];   // [64 rows][128 B] paired-row layout
  __shared__ short Bs[4096];
  const int t = threadIdx.x;
  const int wgid = blockIdx.x;
  const int L = (wgid & 7) * 197 + (wgid >> 3);
  const int m0 = (L >> 3) * 128, o0 = (L & 7) * 128;
  const int l = t & 63, w = t >> 6;
  const int wm = (w >> 1) * 64, wn = (w & 1) * 64;
  const int frow = l & 15, fch = l >> 4;
  const char* Abase = (const char*)(X + (size_t)m0 * K);
  const char* Bbase = (const char*)(Wcat + (size_t)o0 * K);
  const int rb = K * 2;
  char* AsB = (char*)As;
  char* BsB = (char*)Bs;
  const bool ego = (o0 < 512);
  const bool swap = (MODE == 1) && ego;
  f32x4 zero = {0.f, 0.f, 0.f, 0.f};
  f32x4 acc[4][4];
#pragma unroll
  for (int i = 0; i < 4; i++)
#pragma unroll
    for (int j = 0; j < 4; j++) acc[i][j] = zero;
  const int KT = K >> 5;
  for (int kt = 0; kt < KT; kt++) {
    const int kb = kt * 64;
#pragma unroll
    for (int u = 0; u < 2; u++) {
      int prow = u * 32 + (t >> 3);
      int e = (t & 7) ^ (prow & 7);
      int grow = (e >> 2) * 64 + prow;
      size_t goff = (size_t)grow * rb + kb + (e & 3) * 16;
      gll16(Abase + goff, AsB + u * 4096 + t * 16);
      gll16(Bbase + goff, BsB + u * 4096 + t * 16);
    }
    __syncthreads();
    bf16x8 af[4], bfv[4];
#pragma unroll
    for (int i = 0; i < 4; i++) {
      int ar = wm + i * 16 + frow;
      int apr = ar & 63;
      af[i] = *(const bf16x8*)(AsB + apr * 128 + (((((ar >> 6) << 2) | fch) ^ (apr & 7)) * 16));
      int br = wn + i * 16 + frow;
      int bpr = br & 63;
      bfv[i] = *(const bf16x8*)(BsB + bpr * 128 + (((((br >> 6) << 2) | fch) ^ (bpr & 7)) * 16));
    }
    if (!swap) {
#pragma unroll
      for (int i = 0; i < 4; i++)
#pragma unroll
        for (int j = 0; j < 4; j++)
          acc[i][j] = __builtin_amdgcn_mfma_f32_16x16x32_bf16(af[i], bfv[j], acc[i][j], 0, 0, 0);
    } else {
#pragma unroll
      for (int i = 0; i < 4; i++)
#pragma unroll
        for (int j = 0; j < 4; j++)
          acc[i][j] = __builtin_amdgcn_mfma_f32_16x16x32_bf16(bfv[j], af[i], acc[i][j], 0, 0, 0);
    }
    __syncthreads();
  }
  if (ego) {
    if (MODE == 1) {
      // swapped: col(frow)=xrow, row(fch*4+r)=c -> packed uint2 + fused h1-ego pooling
      const int rw = m0 + wm;
      const int b0 = rw / N_;
      const int rloc = (b0 + 1) * N_ - rw;  // local batch boundary (may exceed 64)
#pragma unroll
      for (int j = 0; j < 4; j++) {
        int c0 = o0 + wn + j * 16 + fch * 4;
        float4 b4 = *(const float4*)&biasE[c0];
        float bb4[4] = {b4.x, b4.y, b4.z, b4.w};
        float sA4[4] = {0.f, 0.f, 0.f, 0.f};
        float sB4[4] = {0.f, 0.f, 0.f, 0.f};
#pragma unroll
        for (int i = 0; i < 4; i++) {
          int xloc = i * 16 + frow;
          union { __hip_bfloat16 h[4]; uint2 u; } pk;
#pragma unroll
          for (int r = 0; r < 4; r++) {
            float v = fmaxf(acc[i][j][r] + bb4[r], 0.f);
            pk.h[r] = __float2bfloat16(v);
            if (xloc < rloc) sA4[r] += v; else sB4[r] += v;
          }
          *(uint2*)&h1[(size_t)(rw + xloc) * D2_ + c0] = pk.u;
        }
#pragma unroll
        for (int r = 0; r < 4; r++) {
          float sA = sA4[r], sB = sB4[r];
          sA += __shfl_down(sA, 8, 16); sA += __shfl_down(sA, 4, 16);
          sA += __shfl_down(sA, 2, 16); sA += __shfl_down(sA, 1, 16);
          sB += __shfl_down(sB, 8, 16); sB += __shfl_down(sB, 4, 16);
          sB += __shfl_down(sB, 2, 16); sB += __shfl_down(sB, 1, 16);
          if ((l & 15) == 0) {
            atomicAdd(&pool[(size_t)b0 * D4_ + c0 + r], sA);
            if (rloc < 64) atomicAdd(&pool[(size_t)(b0 + 1) * D4_ + c0 + r], sB);
          }
        }
      }
    } else {
      // normal: col(frow)=c -> pool reduce (batch-boundary aware), offset D2_
#pragma unroll
      for (int j = 0; j < 4; j++) {
        int c = o0 + wn + j * 16 + frow;
        float bv = biasE[c];
        int rw = m0 + wm;
        int b0 = rw / N_;
        int rB = (b0 + 1) * N_;
        float sA = 0.f, sB = 0.f;
#pragma unroll
        for (int i = 0; i < 4; i++) {
          int r0 = m0 + wm + i * 16 + fch * 4;
#pragma unroll
          for (int r = 0; r < 4; r++) {
            float v = fmaxf(acc[i][j][r] + bv, 0.f);
            if (r0 + r < rB) sA += v; else sB += v;
          }
        }
        sA += __shfl_down(sA, 32);
        sA += __shfl_down(sA, 16);
        sB += __shfl_down(sB, 32);
        sB += __shfl_down(sB, 16);
        if (l < 16) {
          atomicAdd(&pool[(size_t)b0 * D4_ + D2_ + c], sA);
          if (rw + 64 > rB) atomicAdd(&pool[(size_t)(b0 + 1) * D4_ + D2_ + c], sB);
        }
      }
    }
  } else {
    // msg half, normal: col(frow)=cm, rows = xrow -> packed along rr
#pragma unroll
    for (int j = 0; j < 4; j++) {
      int cm = (o0 - 512) + wn + j * 16 + frow;
      float bm = biasM[cm];
      __hip_bfloat16* mrow = msgT + (size_t)cm * MT_LD_;
#pragma unroll
      for (int i = 0; i < 4; i++) {
        int x0 = m0 + wm + i * 16 + fch * 4;
        int b0 = x0 / N_;
        int r0 = x0 - b0 * N_;
        union { __hip_bfloat16 h[4]; uint2 u; } pk;
#pragma unroll
        for (int r = 0; r < 4; r++) pk.h[r] = __float2bfloat16(acc[i][j][r] + bm);
        if (r0 + 3 < N_) {
          *(uint2*)&mrow[b0 * KA_ + (b0 & 3) + r0] = pk.u;
        } else {
#pragma unroll
          for (int r = 0; r < 4; r++) {
            int x = x0 + r;
            int bb = x / N_;
            int rx = x - bb * N_;
            mrow[bb * KA_ + (bb & 3) + rx] = pk.h[r];
          }
        }
      }
    }
  }
}

// ---------------- MFMA aggregation: A2[b] @ msgT-slice, BK=32, SWAPPED -> packed h1 ---
template <int MODE>
__global__ __launch_bounds__(256) void mfma_agg(const __hip_bfloat16* __restrict__ A2bf,
                                                const __hip_bfloat16* __restrict__ msgT,
                                                const float* __restrict__ deg,
                                                __hip_bfloat16* __restrict__ h1,
                                                float* __restrict__ pool, int poolOff) {
  __shared__ short As[4096];
  __shared__ short Bs[4096];
  const int t = threadIdx.x;
  const int wgid = blockIdx.x;
  const int L = (wgid & 7) * 128 + (wgid >> 3);
  const int b = L >> 3;
  const int o0 = ((L >> 1) & 3) * 128;
  const int m0 = (L & 1) * 128;
  const int l = t & 63, w = t >> 6;
  const int wm = (w >> 1) * 64, wn = (w & 1) * 64;
  const int frow = l & 15, fch = l >> 4;
  const char* Abase = (const char*)(A2bf + ((size_t)b * NA_ + m0) * KA_);
  const char* Bbase = (const char*)(msgT + (size_t)o0 * MT_LD_ + (size_t)b * KA_);
  char* AsB = (char*)As;
  char* BsB = (char*)Bs;
  f32x4 zero = {0.f, 0.f, 0.f, 0.f};
  f32x4 acc[4][4];
#pragma unroll
  for (int i = 0; i < 4; i++)
#pragma unroll
    for (int j = 0; j < 4; j++) acc[i][j] = zero;
  for (int kt = 0; kt < 7; kt++) {
    const int kb = kt * 64;
#pragma unroll
    for (int u = 0; u < 2; u++) {
      int prow = u * 32 + (t >> 3);
      int e = (t & 7) ^ (prow & 7);
      int grow = (e >> 2) * 64 + prow;
      gll16(Abase + (size_t)grow * (KA_ * 2) + kb + (e & 3) * 16, AsB + u * 4096 + t * 16);
      gll16(Bbase + (size_t)grow * (MT_LD_ * 2) + kb + (e & 3) * 16, BsB + u * 4096 + t * 16);
    }
    __syncthreads();
    bf16x8 af[4], bfv[4];
#pragma unroll
    for (int i = 0; i < 4; i++) {
      int ar = wm + i * 16 + frow;
      int apr = ar & 63;
      af[i] = *(const bf16x8*)(AsB + apr * 128 + (((((ar >> 6) << 2) | fch) ^ (apr & 7)) * 16));
      int br = wn + i * 16 + frow;
      int bpr = br & 63;
      bfv[i] = *(const bf16x8*)(BsB + bpr * 128 + (((((br >> 6) << 2) | fch) ^ (bpr & 7)) * 16));
    }
    // swapped: D col(frow) = A2 row (n), D row(fch*4+r) = msgT row (c)
#pragma unroll
    for (int i = 0; i < 4; i++)
#pragma unroll
      for (int j = 0; j < 4; j++)
        acc[i][j] = __builtin_amdgcn_mfma_f32_16x16x32_bf16(bfv[j], af[i], acc[i][j], 0, 0, 0);
    __syncthreads();
  }
  float sv[4][4];
#pragma unroll
  for (int j = 0; j < 4; j++)
#pragma unroll
    for (int r = 0; r < 4; r++) sv[j][r] = 0.f;
#pragma unroll
  for (int i = 0; i < 4; i++) {
    int n = m0 + wm + i * 16 + frow;
    bool ok = (n < N_);
    float dinv = ok ? (1.f / deg[b * N_ + n]) : 0.f;
#pragma unroll
    for (int j = 0; j < 4; j++) {
      int c0 = o0 + wn + j * 16 + fch * 4;
      union { __hip_bfloat16 h[4]; uint2 u; } pk;
#pragma unroll
      for (int r = 0; r < 4; r++) {
        float v = ok ? fmaxf(acc[i][j][r] * dinv, 0.f) : 0.f;
        sv[j][r] += v;
        pk.h[r] = __float2bfloat16(v);
      }
      if (MODE == 0 && ok)
        *(uint2*)&h1[((size_t)b * N_ + n) * D2_ + NH_ + c0] = pk.u;
    }
  }
#pragma unroll
  for (int j = 0; j < 4; j++) {
#pragma unroll
    for (int r = 0; r < 4; r++) {
      float s = sv[j][r];
      s += __shfl_down(s, 8, 16);
      s += __shfl_down(s, 4, 16);
      s += __shfl_down(s, 2, 16);
      s += __shfl_down(s, 1, 16);
      if ((l & 15) == 0)
        atomicAdd(&pool[(size_t)b * D4_ + poolOff + o0 + wn + j * 16 + fch * 4 + r], s);
    }
  }
}

// ---------------- gf[:, 0:2048] = pool / N ----------------
__global__ __launch_bounds__(256) void scale_pool(const float* __restrict__ pool,
                                                  float* __restrict__ gf) {
  int b = blockIdx.y;
  int c = blockIdx.x * 256 + threadIdx.x;  // 0..2047
  gf[(size_t)b * D4_ + c] = pool[(size_t)b * D4_ + c] * (1.f / N_);
}

// ---------------- head GEMM: split-K f32, atomic accumulate ----------------
template <bool RELUX>
__global__ __launch_bounds__(256) void head_gemm(const float* __restrict__ Xg,
                                                 const float* __restrict__ W,
                                                 const float* __restrict__ bias,
                                                 float* __restrict__ Y,
                                                 int Rows, int Fin, int O, int kchunk) {
  __shared__ float Xs[16][68];
  __shared__ float Ws[16][68];
  int tx = threadIdx.x, ty = threadIdx.y;
  int tid = ty * 16 + tx;
  int lr = tid >> 2;
  int lk = (tid & 3) * 4;
  int rbase = blockIdx.y * 64;
  int o0 = blockIdx.x * 64;
  int k0base = blockIdx.z * kchunk;
  float acc[4][4] = {};
  for (int k0 = k0base; k0 < k0base + kchunk; k0 += 16) {
    float4 xv = make_float4(0.f, 0.f, 0.f, 0.f);
    if (rbase + lr < Rows) xv = *(const float4*)&Xg[(size_t)(rbase + lr) * Fin + k0 + lk];
    if (RELUX) {
      xv.x = fmaxf(xv.x, 0.f); xv.y = fmaxf(xv.y, 0.f);
      xv.z = fmaxf(xv.z, 0.f); xv.w = fmaxf(xv.w, 0.f);
    }
    Xs[lk][lr] = xv.x; Xs[lk + 1][lr] = xv.y; Xs[lk + 2][lr] = xv.z; Xs[lk + 3][lr] = xv.w;
    float4 wv = make_float4(0.f, 0.f, 0.f, 0.f);
    if (o0 + lr < O) wv = *(const float4*)&W[(size_t)(o0 + lr) * Fin + k0 + lk];
    Ws[lk][lr] = wv.x; Ws[lk + 1][lr] = wv.y; Ws[lk + 2][lr] = wv.z; Ws[lk + 3][lr] = wv.w;
    __syncthreads();
#pragma unroll
    for (int k = 0; k < 16; k++) {
      float4 a = *(const float4*)&Xs[k][ty * 4];
      float4 bb = *(const float4*)&Ws[k][tx * 4];
      float av[4] = {a.x, a.y, a.z, a.w};
      float bv[4] = {bb.x, bb.y, bb.z, bb.w};
#pragma unroll
      for (int i = 0; i < 4; i++)
#pragma unroll
        for (int j = 0; j < 4; j++) acc[i][j] = fmaf(av[i], bv[j], acc[i][j]);
    }
    __syncthreads();
  }
#pragma unroll
  for (int i = 0; i < 4; i++) {
    int rrow = rbase + ty * 4 + i;
    if (rrow >= Rows) continue;
#pragma unroll
    for (int j = 0; j < 4; j++) {
      int c = o0 + tx * 4 + j;
      if (c >= O) continue;
      float vv = acc[i][j] + ((blockIdx.z == 0) ? bias[c] : 0.f);
      atomicAdd(&Y[(size_t)rrow * O + c], vv);
    }
  }
}

// ---------------- host launch ----------------
extern "C" void kernel_launch(void* const* d_in, const int* in_sizes, int n_in,
                              void* d_out, int out_size, void* d_ws, size_t ws_size,
                              hipStream_t stream) {
  const float* Fet  = (const float*)d_in[0];
  const float* w1_0 = (const float*)d_in[1];
  const float* b1_0 = (const float*)d_in[2];
  const float* w2_0 = (const float*)d_in[3];
  const float* b2_0 = (const float*)d_in[4];
  const float* w1_1 = (const float*)d_in[5];
  const float* b1_1 = (const float*)d_in[6];
  const float* w2_1 = (const float*)d_in[7];
  const float* b2_1 = (const float*)d_in[8];
  const float* fc1_w = (const float*)d_in[9];
  const float* fc1_b = (const float*)d_in[10];
  const float* fc2_w = (const float*)d_in[11];
  const float* fc2_b = (const float*)d_in[12];

  char* ws = (char*)d_ws;
  float* g0 = (float*)(ws + OFF_G0);
  float* g1 = (float*)(ws + OFF_G1);
  __hip_bfloat16* A2bf = (__hip_bfloat16*)(ws + OFF_G0);  // overlay (g0 dead after topk)
  float* sq = (float*)(ws + OFF_SQ);
  unsigned long long* Abits = (unsigned long long*)(ws + OFF_ABITS);
  float* deg = (float*)(ws + OFF_DEG);
  __hip_bfloat16* Fet_hi = (__hip_bfloat16*)(ws + OFF_FETHI);
  __hip_bfloat16* Fet_lo = (__hip_bfloat16*)(ws + OFF_FETLO);  // overlay msgT/h1 head
  __hip_bfloat16* msgT = (__hip_bfloat16*)(ws + OFF_MSGT);
  __hip_bfloat16* h1 = (__hip_bfloat16*)(ws + OFF_H1);
  float* pool = (float*)(ws + OFF_POOL);
  float* p = (float*)(ws + OFF_P);
  __hip_bfloat16* wc1 = (__hip_bfloat16*)(ws + OFF_WC1);
  __hip_bfloat16* wc2 = (__hip_bfloat16*)(ws + OFF_WC2);

  float* out = (float*)d_out;          // [B, NC]
  float* gf = out + (size_t)B_ * NC_;  // [B, D4]

  hipMemsetAsync(Abits, 0, (size_t)ROWS_ * 4 * sizeof(unsigned long long), stream);
  hipMemsetAsync(pool, 0, (size_t)B_ * D4_ * sizeof(float), stream);
  hipMemsetAsync(p, 0, (size_t)B_ * NH_ * sizeof(float), stream);
  hipMemsetAsync(out, 0, (size_t)B_ * NC_ * sizeof(float), stream);

  // casts
  cast_hilo_sq<<<ROWS_ / 4, 256, 0, stream>>>(Fet, Fet_hi, Fet_lo, sq);
  cast_weights<<<1792, 256, 0, stream>>>(w1_0, w2_0, w1_1, w2_1, wc1, wc2);

  // graph construction
  mfma_gram<<<768, 256, 0, stream>>>(Fet_hi, Fet_lo, g0, g1);
  topk_kernel<<<ROWS_ / 4, 256, 0, stream>>>(g0, g1, sq, Abits);
  a2_kernel<<<ROWS_ / 4, 256, 0, stream>>>(Abits, A2bf, deg);

  // layer 1 (Fet_lo dead from here; msgT/h1 overwrite it). ego1 pool fused in-epilogue.
  mfma_fused<1><<<1576, 256, 0, stream>>>(Fet_hi, wc1, b1_0, b2_0, h1, msgT, pool, F_);
  mfma_agg<0><<<1024, 256, 0, stream>>>(A2bf, msgT, deg, h1, pool, NH_);

  // layer 2 (ego2 pooled in-epilogue; msg2 -> msgT -> agg2 pooled)
  mfma_fused<2><<<1576, 256, 0, stream>>>(h1, wc2, b1_1, b2_1, nullptr, msgT, pool, D2_);
  mfma_agg<1><<<1024, 256, 0, stream>>>(A2bf, msgT, deg, nullptr, pool, D2_ + NH_);

  // pooling -> graph_features (all 2048 cols from pool)
  scale_pool<<<dim3(8, B_), 256, 0, stream>>>(pool, gf);

  // head (f32, split-K + atomics; fc1 relu folded into fc2 X-load)
  head_gemm<false><<<dim3(8, 2, 16), dim3(16, 16), 0, stream>>>(
      gf, fc1_w, fc1_b, p, B_, D4_, NH_, 128);
  head_gemm<true><<<dim3(16, 2, 8), dim3(16, 16), 0, stream>>>(
      p, fc2_w, fc2_b, out, B_, NH_, NC_, 64);
}

// Round 11
// 2298.635 us; speedup vs baseline: 1.0037x; 1.0037x over previous
//
#include <hip/hip_runtime.h>
#include <hip/hip_bf16.h>
#include <math.h>

typedef __attribute__((ext_vector_type(8))) short bf16x8;
typedef __attribute__((ext_vector_type(4))) float f32x4;

#define B_ 128
#define N_ 197
#define F_ 768
#define NH_ 512
#define D2_ 1024
#define D4_ 2048
#define NC_ 1000
#define ROWS_ (B_ * N_)   // 25216 = 197 * 128
#define KA_ 224           // agg K padded per batch (197 -> 224), per-batch phase pad b&3
#define NA_ 256           // agg node rows padded
#define LDG_ 200          // gram leading dim (197 -> 200, mult of 4 for f32x4 stores)
#define MT_LD_ (B_ * KA_) // msgT row length: 128*224 = 28672

// workspace offsets (bytes). g0 overlays A2bf (g0 dead after topk). Fet_lo overlays
// msgT+h1 head (lo dead after gram; stale msgT pad bytes are finite bf16, killed by A2 zeros).
#define OFF_G0     0ull           // [25216][200] f32 = 20,172,800
#define OFF_SQ     20172800ull
#define OFF_ABITS  20273664ull    // [25216][4] u64
#define OFF_DEG    21080576ull
#define OFF_FETHI  21181440ull    // [25280][768] bf16
#define OFF_MSGT   60011520ull    // [512][28672] bf16 = 29,360,128
#define OFF_H1     89371648ull    // [25216][1024] bf16
#define OFF_FETLO  OFF_MSGT       // overlay
#define OFF_POOL   141014016ull   // [128][2048] f32
#define OFF_P      142062592ull   // [128][512] f32
#define OFF_WC1    142324736ull   // [1024][768] bf16
#define OFF_WC2    143897600ull   // [1024][1024] bf16
#define OFF_G1     145994752ull   // [25216][200] f32, end 166,167,552

__device__ __forceinline__ void gll16(const void* g, void* l) {
  __builtin_amdgcn_global_load_lds((const __attribute__((address_space(1))) void*)g,
                                   (__attribute__((address_space(3))) void*)l, 16, 0, 0);
}

// Paired-row LDS layout for a 128row x 64B tile stored as [64][128B]:
// logical (row ar, 16B-chunk fch) lives at phys row (ar&63),
// slot ((ar>>6)*4 + fch) ^ ((ar&63)&7). Conflict-free (2-way) ds_read_b128.

// ---------------- all four weight casts in one launch ----------------
__global__ __launch_bounds__(256) void cast_weights(const float* __restrict__ w10,
                                                    const float* __restrict__ w20,
                                                    const float* __restrict__ w11,
                                                    const float* __restrict__ w21,
                                                    __hip_bfloat16* __restrict__ wc1,
                                                    __hip_bfloat16* __restrict__ wc2) {
  const int S1 = NH_ * F_ / 4;   // 98304
  const int S2 = NH_ * D2_ / 4;  // 131072
  int i = blockIdx.x * 256 + threadIdx.x;
  const float* src;
  __hip_bfloat16* dst;
  int off;
  if (i < S1) { src = w10; dst = wc1; off = i; }
  else if (i < 2 * S1) { src = w20; dst = wc1 + (size_t)NH_ * F_; off = i - S1; }
  else if (i < 2 * S1 + S2) { src = w11; dst = wc2; off = i - 2 * S1; }
  else { src = w21; dst = wc2 + (size_t)NH_ * D2_; off = i - 2 * S1 - S2; }
  float4 v = ((const float4*)src)[off];
  union { __hip_bfloat16 h[4]; uint2 u; } pk;
  pk.h[0] = __float2bfloat16(v.x);
  pk.h[1] = __float2bfloat16(v.y);
  pk.h[2] = __float2bfloat16(v.z);
  pk.h[3] = __float2bfloat16(v.w);
  ((uint2*)dst)[off] = pk.u;
}

// ---------------- f32 -> bf16 hi/lo split + squared norms (one Fet read) ----------------
__global__ __launch_bounds__(256) void cast_hilo_sq(const float* __restrict__ X,
                                                    __hip_bfloat16* __restrict__ hi,
                                                    __hip_bfloat16* __restrict__ lo,
                                                    float* __restrict__ sq) {
  int row = blockIdx.x * 4 + (threadIdx.x >> 6);
  int lane = threadIdx.x & 63;
  const float4* xp = (const float4*)(X + (size_t)row * F_);
  uint2* hp = (uint2*)(hi + (size_t)row * F_);
  uint2* lp = (uint2*)(lo + (size_t)row * F_);
  float s = 0.f;
#pragma unroll
  for (int i = 0; i < 3; i++) {
    float4 v = xp[lane + i * 64];
    s += v.x * v.x + v.y * v.y + v.z * v.z + v.w * v.w;
    float f[4] = {v.x, v.y, v.z, v.w};
    union { __hip_bfloat16 h[4]; uint2 u; } ph, pl;
#pragma unroll
    for (int k = 0; k < 4; k++) {
      __hip_bfloat16 h = __float2bfloat16(f[k]);
      ph.h[k] = h;
      pl.h[k] = __float2bfloat16(f[k] - __bfloat162float(h));
    }
    hp[lane + i * 64] = ph.u;
    lp[lane + i * 64] = pl.u;
  }
#pragma unroll
  for (int o = 32; o > 0; o >>= 1) s += __shfl_down(s, o);
  if (lane == 0) sq[row] = s;
}

// ---------------- pairwise Gram via MFMA, split-bf16 3-pass, K-split x2 (BK=32) -------
__global__ __launch_bounds__(256) void mfma_gram(const __hip_bfloat16* __restrict__ Xhi,
                                                 const __hip_bfloat16* __restrict__ Xlo,
                                                 float* __restrict__ g0,
                                                 float* __restrict__ g1) {
  __shared__ short AsH[4096];
  __shared__ short BsH[4096];
  __shared__ short AsL[4096];
  __shared__ short BsL[4096];
  const int t = threadIdx.x;
  const int wgid = blockIdx.x;
  const int L = (wgid & 7) * 96 + (wgid >> 3);
  const int b = L / 6;
  const int rbx = L - b * 6;
  const int bx = rbx % 3;
  const int khalf = rbx / 3;
  const int m0 = (bx == 0) ? 0 : 128;
  const int o0 = (bx == 2) ? 128 : 0;
  const bool mirror = (bx == 1);
  const int l = t & 63, w = t >> 6;
  const int wm = (w >> 1) * 64, wn = (w & 1) * 64;
  const int frow = l & 15, fch = l >> 4;
  const size_t rowbase = (size_t)b * N_;
  const char* AhiB = (const char*)(Xhi + (rowbase + m0) * F_);
  const char* AloB = (const char*)(Xlo + (rowbase + m0) * F_);
  const char* BhiB = (const char*)(Xhi + (rowbase + o0) * F_);
  const char* BloB = (const char*)(Xlo + (rowbase + o0) * F_);
  const int rb = F_ * 2;
  char* AsHB = (char*)AsH;
  char* BsHB = (char*)BsH;
  char* AsLB = (char*)AsL;
  char* BsLB = (char*)BsL;
  float* go = khalf ? g1 : g0;
  f32x4 zero = {0.f, 0.f, 0.f, 0.f};
  f32x4 acc[4][4];
#pragma unroll
  for (int i = 0; i < 4; i++)
#pragma unroll
    for (int j = 0; j < 4; j++) acc[i][j] = zero;
  const int kt0 = khalf * 12;
  for (int kt = kt0; kt < kt0 + 12; kt++) {
    const int kb = kt * 64;
#pragma unroll
    for (int u = 0; u < 2; u++) {
      int prow = u * 32 + (t >> 3);
      int e = (t & 7) ^ (prow & 7);
      int grow = (e >> 2) * 64 + prow;
      size_t goff = (size_t)grow * rb + kb + (e & 3) * 16;
      gll16(AhiB + goff, AsHB + u * 4096 + t * 16);
      gll16(BhiB + goff, BsHB + u * 4096 + t * 16);
      gll16(AloB + goff, AsLB + u * 4096 + t * 16);
      gll16(BloB + goff, BsLB + u * 4096 + t * 16);
    }
    __syncthreads();
    bf16x8 ah[4], al[4], bh[4], bl[4];
#pragma unroll
    for (int i = 0; i < 4; i++) {
      int ar = wm + i * 16 + frow;
      int apr = ar & 63;
      int aoff = apr * 128 + (((((ar >> 6) << 2) | fch) ^ (apr & 7)) * 16);
      ah[i] = *(const bf16x8*)(AsHB + aoff);
      al[i] = *(const bf16x8*)(AsLB + aoff);
      int br = wn + i * 16 + frow;
      int bpr = br & 63;
      int boff = bpr * 128 + (((((br >> 6) << 2) | fch) ^ (bpr & 7)) * 16);
      bh[i] = *(const bf16x8*)(BsHB + boff);
      bl[i] = *(const bf16x8*)(BsLB + boff);
    }
    // swapped: D col = A-tile row (n), D row = B-tile row (m)
#pragma unroll
    for (int i = 0; i < 4; i++)
#pragma unroll
      for (int j = 0; j < 4; j++) {
        acc[i][j] = __builtin_amdgcn_mfma_f32_16x16x32_bf16(bh[j], ah[i], acc[i][j], 0, 0, 0);
        acc[i][j] = __builtin_amdgcn_mfma_f32_16x16x32_bf16(bl[j], ah[i], acc[i][j], 0, 0, 0);
        acc[i][j] = __builtin_amdgcn_mfma_f32_16x16x32_bf16(bh[j], al[i], acc[i][j], 0, 0, 0);
      }
    __syncthreads();
  }
#pragma unroll
  for (int i = 0; i < 4; i++) {
    int n = m0 + wm + i * 16 + frow;
    if (n >= N_) continue;
    float* gr = go + (rowbase + n) * LDG_;
#pragma unroll
    for (int j = 0; j < 4; j++) {
      int mb = o0 + wn + j * 16 + fch * 4;
      if (mb >= LDG_) continue;
      f32x4 pv = acc[i][j];
      *(f32x4*)&gr[mb] = pv;
      if (mirror) {
#pragma unroll
        for (int r = 0; r < 4; r++)
          go[(rowbase + mb + r) * LDG_ + n] = pv[r];
      }
    }
  }
}

// ---------------- top-4 per row -> symmetric adjacency bitmask ----------------
__global__ __launch_bounds__(256) void topk_kernel(const float* __restrict__ g0,
                                                   const float* __restrict__ g1,
                                                   const float* __restrict__ sq,
                                                   unsigned long long* __restrict__ Abits) {
  int row = blockIdx.x * 4 + (threadIdx.x >> 6);
  int lane = threadIdx.x & 63;
  int b = row / N_, n = row - b * N_;
  const float* g0r = g0 + (size_t)row * LDG_;
  const float* g1r = g1 + (size_t)row * LDG_;
  const float* sqb = sq + (size_t)b * N_;
  float v[4];
  int vi[4];
#pragma unroll
  for (int i = 0; i < 4; i++) {
    int m = lane + i * 64;
    bool ok = (m < N_) && (m != n);
    v[i] = ok ? (sqb[m] - 2.f * (g0r[m] + g1r[m])) : INFINITY;
    vi[i] = ok ? m : 0x3fffffff;
  }
  unsigned long long nbr[4] = {0ull, 0ull, 0ull, 0ull};
#pragma unroll
  for (int t = 0; t < 4; t++) {
    float bv = v[0];
    int bi = vi[0];
#pragma unroll
    for (int i = 1; i < 4; i++)
      if (v[i] < bv || (v[i] == bv && vi[i] < bi)) { bv = v[i]; bi = vi[i]; }
#pragma unroll
    for (int o = 1; o < 64; o <<= 1) {
      float ov = __shfl_xor(bv, o);
      int oi = __shfl_xor(bi, o);
      if (ov < bv || (ov == bv && oi < bi)) { bv = ov; bi = oi; }
    }
#pragma unroll
    for (int i = 0; i < 4; i++)
      if (vi[i] == bi) { v[i] = INFINITY; vi[i] = 0x3fffffff; }
    if (lane == 0) {
      nbr[bi >> 6] |= 1ull << (bi & 63);
      atomicOr(&Abits[((size_t)b * N_ + bi) * 4 + (n >> 6)], 1ull << (n & 63));
    }
  }
  if (lane == 0) {
#pragma unroll
    for (int w = 0; w < 4; w++)
      if (nbr[w]) atomicOr(&Abits[(size_t)row * 4 + w], nbr[w]);
  }
}

// ---------------- 2-hop adjacency -> bf16 [B][256][224] (phase-shift b&3) + deg -------
__global__ __launch_bounds__(256) void a2_kernel(const unsigned long long* __restrict__ Abits,
                                                 __hip_bfloat16* __restrict__ A2bf,
                                                 float* __restrict__ deg) {
  int row = blockIdx.x * 4 + (threadIdx.x >> 6);
  int lane = threadIdx.x & 63;
  int b = row / N_, n = row - b * N_;
  const unsigned long long* arow = Abits + (size_t)row * 4;
  const unsigned long long* base = Abits + (size_t)b * N_ * 4;
  unsigned long long r0 = 0, r1 = 0, r2 = 0, r3 = 0;
#pragma unroll
  for (int w = 0; w < 4; w++) {
    if ((arow[w] >> lane) & 1ull) {
      const unsigned long long* mr = base + (size_t)(w * 64 + lane) * 4;
      r0 |= mr[0]; r1 |= mr[1]; r2 |= mr[2]; r3 |= mr[3];
    }
  }
#pragma unroll
  for (int o = 1; o < 64; o <<= 1) {
    r0 |= __shfl_xor(r0, o);
    r1 |= __shfl_xor(r1, o);
    r2 |= __shfl_xor(r2, o);
    r3 |= __shfl_xor(r3, o);
  }
  unsigned long long rr[4] = {r0, r1, r2, r3};
  rr[n >> 6] &= ~(1ull << (n & 63));
  const int pad = b & 3;
  __hip_bfloat16* out = A2bf + ((size_t)b * NA_ + n) * KA_;
  const __hip_bfloat16 one = __float2bfloat16(1.f);
  const __hip_bfloat16 zer = __float2bfloat16(0.f);
#pragma unroll
  for (int i = 0; i < 4; i++) {
    int m = lane + i * 64;
    if (m < KA_) {
      int k = m - pad;
      bool bit = (k >= 0 && k < N_ && ((rr[k >> 6] >> (k & 63)) & 1ull));
      out[m] = bit ? one : zer;
    }
  }
  if (lane == 0) {
    int dg = __popcll(rr[0]) + __popcll(rr[1]) + __popcll(rr[2]) + __popcll(rr[3]);
    deg[row] = (float)(dg > 0 ? dg : 1);
  }
}

// ---------------- merged ego+msg GEMM over concat weights [1024][K], BK=32 ------------
// __launch_bounds__(256, 6): cap VGPR ~85 so 6 blocks/CU -> 1536 resident, single-round
// grid (1576 blocks). At 5/CU the grid ran 1.23 rounds (23% tail at ~1/5 utilization).
template <int MODE>
__global__ __launch_bounds__(256, 6) void mfma_fused(const __hip_bfloat16* __restrict__ X,
                                                     const __hip_bfloat16* __restrict__ Wcat,
                                                     const float* __restrict__ biasE,
                                                     const float* __restrict__ biasM,
                                                     __hip_bfloat16* __restrict__ h1,
                                                     __hip_bfloat16* __restrict__ msgT,
                                                     float* __restrict__ pool,
                                                     int K) {
  __shared__ short As[4096];   // [64 rows][128 B] paired-row layout
  __shared__ short Bs[4096];
  const int t = threadIdx.x;
  const int wgid = blockIdx.x;
  const int L = (wgid & 7) * 197 + (wgid >> 3);
  const int m0 = (L >> 3) * 128, o0 = (L & 7) * 128;
  const int l = t & 63, w = t >> 6;
  const int wm = (w >> 1) * 64, wn = (w & 1) * 64;
  const int frow = l & 15, fch = l >> 4;
  const char* Abase = (const char*)(X + (size_t)m0 * K);
  const char* Bbase = (const char*)(Wcat + (size_t)o0 * K);
  const int rb = K * 2;
  char* AsB = (char*)As;
  char* BsB = (char*)Bs;
  const bool ego = (o0 < 512);
  const bool swap = (MODE == 1) && ego;
  f32x4 zero = {0.f, 0.f, 0.f, 0.f};
  f32x4 acc[4][4];
#pragma unroll
  for (int i = 0; i < 4; i++)
#pragma unroll
    for (int j = 0; j < 4; j++) acc[i][j] = zero;
  const int KT = K >> 5;
  for (int kt = 0; kt < KT; kt++) {
    const int kb = kt * 64;
#pragma unroll
    for (int u = 0; u < 2; u++) {
      int prow = u * 32 + (t >> 3);
      int e = (t & 7) ^ (prow & 7);
      int grow = (e >> 2) * 64 + prow;
      size_t goff = (size_t)grow * rb + kb + (e & 3) * 16;
      gll16(Abase + goff, AsB + u * 4096 + t * 16);
      gll16(Bbase + goff, BsB + u * 4096 + t * 16);
    }
    __syncthreads();
    bf16x8 af[4], bfv[4];
#pragma unroll
    for (int i = 0; i < 4; i++) {
      int ar = wm + i * 16 + frow;
      int apr = ar & 63;
      af[i] = *(const bf16x8*)(AsB + apr * 128 + (((((ar >> 6) << 2) | fch) ^ (apr & 7)) * 16));
      int br = wn + i * 16 + frow;
      int bpr = br & 63;
      bfv[i] = *(const bf16x8*)(BsB + bpr * 128 + (((((br >> 6) << 2) | fch) ^ (bpr & 7)) * 16));
    }
    if (!swap) {
#pragma unroll
      for (int i = 0; i < 4; i++)
#pragma unroll
        for (int j = 0; j < 4; j++)
          acc[i][j] = __builtin_amdgcn_mfma_f32_16x16x32_bf16(af[i], bfv[j], acc[i][j], 0, 0, 0);
    } else {
#pragma unroll
      for (int i = 0; i < 4; i++)
#pragma unroll
        for (int j = 0; j < 4; j++)
          acc[i][j] = __builtin_amdgcn_mfma_f32_16x16x32_bf16(bfv[j], af[i], acc[i][j], 0, 0, 0);
    }
    __syncthreads();
  }
  if (ego) {
    if (MODE == 1) {
      // swapped: col(frow)=xrow, row(fch*4+r)=c -> packed uint2 + fused h1-ego pooling
      const int rw = m0 + wm;
      const int b0 = rw / N_;
      const int rloc = (b0 + 1) * N_ - rw;  // local batch boundary (may exceed 64)
#pragma unroll
      for (int j = 0; j < 4; j++) {
        int c0 = o0 + wn + j * 16 + fch * 4;
        float4 b4 = *(const float4*)&biasE[c0];
        float bb4[4] = {b4.x, b4.y, b4.z, b4.w};
        float sA4[4] = {0.f, 0.f, 0.f, 0.f};
        float sB4[4] = {0.f, 0.f, 0.f, 0.f};
#pragma unroll
        for (int i = 0; i < 4; i++) {
          int xloc = i * 16 + frow;
          union { __hip_bfloat16 h[4]; uint2 u; } pk;
#pragma unroll
          for (int r = 0; r < 4; r++) {
            float v = fmaxf(acc[i][j][r] + bb4[r], 0.f);
            pk.h[r] = __float2bfloat16(v);
            if (xloc < rloc) sA4[r] += v; else sB4[r] += v;
          }
          *(uint2*)&h1[(size_t)(rw + xloc) * D2_ + c0] = pk.u;
        }
#pragma unroll
        for (int r = 0; r < 4; r++) {
          float sA = sA4[r], sB = sB4[r];
          sA += __shfl_down(sA, 8, 16); sA += __shfl_down(sA, 4, 16);
          sA += __shfl_down(sA, 2, 16); sA += __shfl_down(sA, 1, 16);
          sB += __shfl_down(sB, 8, 16); sB += __shfl_down(sB, 4, 16);
          sB += __shfl_down(sB, 2, 16); sB += __shfl_down(sB, 1, 16);
          if ((l & 15) == 0) {
            atomicAdd(&pool[(size_t)b0 * D4_ + c0 + r], sA);
            if (rloc < 64) atomicAdd(&pool[(size_t)(b0 + 1) * D4_ + c0 + r], sB);
          }
        }
      }
    } else {
      // normal: col(frow)=c -> pool reduce (batch-boundary aware), offset D2_
#pragma unroll
      for (int j = 0; j < 4; j++) {
        int c = o0 + wn + j * 16 + frow;
        float bv = biasE[c];
        int rw = m0 + wm;
        int b0 = rw / N_;
        int rB = (b0 + 1) * N_;
        float sA = 0.f, sB = 0.f;
#pragma unroll
        for (int i = 0; i < 4; i++) {
          int r0 = m0 + wm + i * 16 + fch * 4;
#pragma unroll
          for (int r = 0; r < 4; r++) {
            float v = fmaxf(acc[i][j][r] + bv, 0.f);
            if (r0 + r < rB) sA += v; else sB += v;
          }
        }
        sA += __shfl_down(sA, 32);
        sA += __shfl_down(sA, 16);
        sB += __shfl_down(sB, 32);
        sB += __shfl_down(sB, 16);
        if (l < 16) {
          atomicAdd(&pool[(size_t)b0 * D4_ + D2_ + c], sA);
          if (rw + 64 > rB) atomicAdd(&pool[(size_t)(b0 + 1) * D4_ + D2_ + c], sB);
        }
      }
    }
  } else {
    // msg half, normal: col(frow)=cm, rows = xrow -> packed along rr
#pragma unroll
    for (int j = 0; j < 4; j++) {
      int cm = (o0 - 512) + wn + j * 16 + frow;
      float bm = biasM[cm];
      __hip_bfloat16* mrow = msgT + (size_t)cm * MT_LD_;
#pragma unroll
      for (int i = 0; i < 4; i++) {
        int x0 = m0 + wm + i * 16 + fch * 4;
        int b0 = x0 / N_;
        int r0 = x0 - b0 * N_;
        union { __hip_bfloat16 h[4]; uint2 u; } pk;
#pragma unroll
        for (int r = 0; r < 4; r++) pk.h[r] = __float2bfloat16(acc[i][j][r] + bm);
        if (r0 + 3 < N_) {
          *(uint2*)&mrow[b0 * KA_ + (b0 & 3) + r0] = pk.u;
        } else {
#pragma unroll
          for (int r = 0; r < 4; r++) {
            int x = x0 + r;
            int bb = x / N_;
            int rx = x - bb * N_;
            mrow[bb * KA_ + (bb & 3) + rx] = pk.h[r];
          }
        }
      }
    }
  }
}

// ---------------- MFMA aggregation: A2[b] @ msgT-slice, BK=32, SWAPPED -> packed h1 ---
template <int MODE>
__global__ __launch_bounds__(256) void mfma_agg(const __hip_bfloat16* __restrict__ A2bf,
                                                const __hip_bfloat16* __restrict__ msgT,
                                                const float* __restrict__ deg,
                                                __hip_bfloat16* __restrict__ h1,
                                                float* __restrict__ pool, int poolOff) {
  __shared__ short As[4096];
  __shared__ short Bs[4096];
  const int t = threadIdx.x;
  const int wgid = blockIdx.x;
  const int L = (wgid & 7) * 128 + (wgid >> 3);
  const int b = L >> 3;
  const int o0 = ((L >> 1) & 3) * 128;
  const int m0 = (L & 1) * 128;
  const int l = t & 63, w = t >> 6;
  const int wm = (w >> 1) * 64, wn = (w & 1) * 64;
  const int frow = l & 15, fch = l >> 4;
  const char* Abase = (const char*)(A2bf + ((size_t)b * NA_ + m0) * KA_);
  const char* Bbase = (const char*)(msgT + (size_t)o0 * MT_LD_ + (size_t)b * KA_);
  char* AsB = (char*)As;
  char* BsB = (char*)Bs;
  f32x4 zero = {0.f, 0.f, 0.f, 0.f};
  f32x4 acc[4][4];
#pragma unroll
  for (int i = 0; i < 4; i++)
#pragma unroll
    for (int j = 0; j < 4; j++) acc[i][j] = zero;
  for (int kt = 0; kt < 7; kt++) {
    const int kb = kt * 64;
#pragma unroll
    for (int u = 0; u < 2; u++) {
      int prow = u * 32 + (t >> 3);
      int e = (t & 7) ^ (prow & 7);
      int grow = (e >> 2) * 64 + prow;
      gll16(Abase + (size_t)grow * (KA_ * 2) + kb + (e & 3) * 16, AsB + u * 4096 + t * 16);
      gll16(Bbase + (size_t)grow * (MT_LD_ * 2) + kb + (e & 3) * 16, BsB + u * 4096 + t * 16);
    }
    __syncthreads();
    bf16x8 af[4], bfv[4];
#pragma unroll
    for (int i = 0; i < 4; i++) {
      int ar = wm + i * 16 + frow;
      int apr = ar & 63;
      af[i] = *(const bf16x8*)(AsB + apr * 128 + (((((ar >> 6) << 2) | fch) ^ (apr & 7)) * 16));
      int br = wn + i * 16 + frow;
      int bpr = br & 63;
      bfv[i] = *(const bf16x8*)(BsB + bpr * 128 + (((((br >> 6) << 2) | fch) ^ (bpr & 7)) * 16));
    }
    // swapped: D col(frow) = A2 row (n), D row(fch*4+r) = msgT row (c)
#pragma unroll
    for (int i = 0; i < 4; i++)
#pragma unroll
      for (int j = 0; j < 4; j++)
        acc[i][j] = __builtin_amdgcn_mfma_f32_16x16x32_bf16(bfv[j], af[i], acc[i][j], 0, 0, 0);
    __syncthreads();
  }
  float sv[4][4];
#pragma unroll
  for (int j = 0; j < 4; j++)
#pragma unroll
    for (int r = 0; r < 4; r++) sv[j][r] = 0.f;
#pragma unroll
  for (int i = 0; i < 4; i++) {
    int n = m0 + wm + i * 16 + frow;
    bool ok = (n < N_);
    float dinv = ok ? (1.f / deg[b * N_ + n]) : 0.f;
#pragma unroll
    for (int j = 0; j < 4; j++) {
      int c0 = o0 + wn + j * 16 + fch * 4;
      union { __hip_bfloat16 h[4]; uint2 u; } pk;
#pragma unroll
      for (int r = 0; r < 4; r++) {
        float v = ok ? fmaxf(acc[i][j][r] * dinv, 0.f) : 0.f;
        sv[j][r] += v;
        pk.h[r] = __float2bfloat16(v);
      }
      if (MODE == 0 && ok)
        *(uint2*)&h1[((size_t)b * N_ + n) * D2_ + NH_ + c0] = pk.u;
    }
  }
#pragma unroll
  for (int j = 0; j < 4; j++) {
#pragma unroll
    for (int r = 0; r < 4; r++) {
      float s = sv[j][r];
      s += __shfl_down(s, 8, 16);
      s += __shfl_down(s, 4, 16);
      s += __shfl_down(s, 2, 16);
      s += __shfl_down(s, 1, 16);
      if ((l & 15) == 0)
        atomicAdd(&pool[(size_t)b * D4_ + poolOff + o0 + wn + j * 16 + fch * 4 + r], s);
    }
  }
}

// ---------------- gf[:, 0:2048] = pool / N ----------------
__global__ __launch_bounds__(256) void scale_pool(const float* __restrict__ pool,
                                                  float* __restrict__ gf) {
  int b = blockIdx.y;
  int c = blockIdx.x * 256 + threadIdx.x;  // 0..2047
  gf[(size_t)b * D4_ + c] = pool[(size_t)b * D4_ + c] * (1.f / N_);
}

// ---------------- head GEMM: split-K f32, atomic accumulate ----------------
template <bool RELUX>
__global__ __launch_bounds__(256) void head_gemm(const float* __restrict__ Xg,
                                                 const float* __restrict__ W,
                                                 const float* __restrict__ bias,
                                                 float* __restrict__ Y,
                                                 int Rows, int Fin, int O, int kchunk) {
  __shared__ float Xs[16][68];
  __shared__ float Ws[16][68];
  int tx = threadIdx.x, ty = threadIdx.y;
  int tid = ty * 16 + tx;
  int lr = tid >> 2;
  int lk = (tid & 3) * 4;
  int rbase = blockIdx.y * 64;
  int o0 = blockIdx.x * 64;
  int k0base = blockIdx.z * kchunk;
  float acc[4][4] = {};
  for (int k0 = k0base; k0 < k0base + kchunk; k0 += 16) {
    float4 xv = make_float4(0.f, 0.f, 0.f, 0.f);
    if (rbase + lr < Rows) xv = *(const float4*)&Xg[(size_t)(rbase + lr) * Fin + k0 + lk];
    if (RELUX) {
      xv.x = fmaxf(xv.x, 0.f); xv.y = fmaxf(xv.y, 0.f);
      xv.z = fmaxf(xv.z, 0.f); xv.w = fmaxf(xv.w, 0.f);
    }
    Xs[lk][lr] = xv.x; Xs[lk + 1][lr] = xv.y; Xs[lk + 2][lr] = xv.z; Xs[lk + 3][lr] = xv.w;
    float4 wv = make_float4(0.f, 0.f, 0.f, 0.f);
    if (o0 + lr < O) wv = *(const float4*)&W[(size_t)(o0 + lr) * Fin + k0 + lk];
    Ws[lk][lr] = wv.x; Ws[lk + 1][lr] = wv.y; Ws[lk + 2][lr] = wv.z; Ws[lk + 3][lr] = wv.w;
    __syncthreads();
#pragma unroll
    for (int k = 0; k < 16; k++) {
      float4 a = *(const float4*)&Xs[k][ty * 4];
      float4 bb = *(const float4*)&Ws[k][tx * 4];
      float av[4] = {a.x, a.y, a.z, a.w};
      float bv[4] = {bb.x, bb.y, bb.z, bb.w};
#pragma unroll
      for (int i = 0; i < 4; i++)
#pragma unroll
        for (int j = 0; j < 4; j++) acc[i][j] = fmaf(av[i], bv[j], acc[i][j]);
    }
    __syncthreads();
  }
#pragma unroll
  for (int i = 0; i < 4; i++) {
    int rrow = rbase + ty * 4 + i;
    if (rrow >= Rows) continue;
#pragma unroll
    for (int j = 0; j < 4; j++) {
      int c = o0 + tx * 4 + j;
      if (c >= O) continue;
      float vv = acc[i][j] + ((blockIdx.z == 0) ? bias[c] : 0.f);
      atomicAdd(&Y[(size_t)rrow * O + c], vv);
    }
  }
}

// ---------------- host launch ----------------
extern "C" void kernel_launch(void* const* d_in, const int* in_sizes, int n_in,
                              void* d_out, int out_size, void* d_ws, size_t ws_size,
                              hipStream_t stream) {
  const float* Fet  = (const float*)d_in[0];
  const float* w1_0 = (const float*)d_in[1];
  const float* b1_0 = (const float*)d_in[2];
  const float* w2_0 = (const float*)d_in[3];
  const float* b2_0 = (const float*)d_in[4];
  const float* w1_1 = (const float*)d_in[5];
  const float* b1_1 = (const float*)d_in[6];
  const float* w2_1 = (const float*)d_in[7];
  const float* b2_1 = (const float*)d_in[8];
  const float* fc1_w = (const float*)d_in[9];
  const float* fc1_b = (const float*)d_in[10];
  const float* fc2_w = (const float*)d_in[11];
  const float* fc2_b = (const float*)d_in[12];

  char* ws = (char*)d_ws;
  float* g0 = (float*)(ws + OFF_G0);
  float* g1 = (float*)(ws + OFF_G1);
  __hip_bfloat16* A2bf = (__hip_bfloat16*)(ws + OFF_G0);  // overlay (g0 dead after topk)
  float* sq = (float*)(ws + OFF_SQ);
  unsigned long long* Abits = (unsigned long long*)(ws + OFF_ABITS);
  float* deg = (float*)(ws + OFF_DEG);
  __hip_bfloat16* Fet_hi = (__hip_bfloat16*)(ws + OFF_FETHI);
  __hip_bfloat16* Fet_lo = (__hip_bfloat16*)(ws + OFF_FETLO);  // overlay msgT/h1 head
  __hip_bfloat16* msgT = (__hip_bfloat16*)(ws + OFF_MSGT);
  __hip_bfloat16* h1 = (__hip_bfloat16*)(ws + OFF_H1);
  float* pool = (float*)(ws + OFF_POOL);
  float* p = (float*)(ws + OFF_P);
  __hip_bfloat16* wc1 = (__hip_bfloat16*)(ws + OFF_WC1);
  __hip_bfloat16* wc2 = (__hip_bfloat16*)(ws + OFF_WC2);

  float* out = (float*)d_out;          // [B, NC]
  float* gf = out + (size_t)B_ * NC_;  // [B, D4]

  hipMemsetAsync(Abits, 0, (size_t)ROWS_ * 4 * sizeof(unsigned long long), stream);
  hipMemsetAsync(pool, 0, (size_t)B_ * D4_ * sizeof(float), stream);
  hipMemsetAsync(p, 0, (size_t)B_ * NH_ * sizeof(float), stream);
  hipMemsetAsync(out, 0, (size_t)B_ * NC_ * sizeof(float), stream);

  // casts
  cast_hilo_sq<<<ROWS_ / 4, 256, 0, stream>>>(Fet, Fet_hi, Fet_lo, sq);
  cast_weights<<<1792, 256, 0, stream>>>(w1_0, w2_0, w1_1, w2_1, wc1, wc2);

  // graph construction
  mfma_gram<<<768, 256, 0, stream>>>(Fet_hi, Fet_lo, g0, g1);
  topk_kernel<<<ROWS_ / 4, 256, 0, stream>>>(g0, g1, sq, Abits);
  a2_kernel<<<ROWS_ / 4, 256, 0, stream>>>(Abits, A2bf, deg);

  // layer 1 (Fet_lo dead from here; msgT/h1 overwrite it). ego1 pool fused in-epilogue.
  mfma_fused<1><<<1576, 256, 0, stream>>>(Fet_hi, wc1, b1_0, b2_0, h1, msgT, pool, F_);
  mfma_agg<0><<<1024, 256, 0, stream>>>(A2bf, msgT, deg, h1, pool, NH_);

  // layer 2 (ego2 pooled in-epilogue; msg2 -> msgT -> agg2 pooled)
  mfma_fused<2><<<1576, 256, 0, stream>>>(h1, wc2, b1_1, b2_1, nullptr, msgT, pool, D2_);
  mfma_agg<1><<<1024, 256, 0, stream>>>(A2bf, msgT, deg, nullptr, pool, D2_ + NH_);

  // pooling -> graph_features (all 2048 cols from pool)
  scale_pool<<<dim3(8, B_), 256, 0, stream>>>(pool, gf);

  // head (f32, split-K + atomics; fc1 relu folded into fc2 X-load)
  head_gemm<false><<<dim3(8, 2, 16), dim3(16, 16), 0, stream>>>(
      gf, fc1_w, fc1_b, p, B_, D4_, NH_, 128);
  head_gemm<true><<<dim3(16, 2, 8), dim3(16, 16), 0, stream>>>(
      p, fc2_w, fc2_b, out, B_, NH_, NC_, 64);
}

// Round 12
// 439.962 us; speedup vs baseline: 5.2437x; 5.2246x over previous
//
#include <hip/hip_runtime.h>
#include <hip/hip_bf16.h>
#include <math.h>

typedef __attribute__((ext_vector_type(8))) short bf16x8;
typedef __attribute__((ext_vector_type(4))) float f32x4;

#define B_ 128
#define N_ 197
#define F_ 768
#define NH_ 512
#define D2_ 1024
#define D4_ 2048
#define NC_ 1000
#define ROWS_ (B_ * N_)   // 25216 = 197 * 128
#define KA_ 224           // agg K padded per batch (197 -> 224), per-batch phase pad b&3
#define NA_ 256           // agg node rows padded
#define LDG_ 200          // gram leading dim (197 -> 200, mult of 4 for f32x4 stores)
#define MT_LD_ (B_ * KA_) // msgT row length: 128*224 = 28672

// workspace offsets (bytes). g0 overlays A2bf (g0 dead after topk). Fet_lo overlays
// msgT+h1 head (lo dead after gram; stale msgT pad bytes are finite bf16, killed by A2 zeros).
#define OFF_G0     0ull           // [25216][200] f32 = 20,172,800
#define OFF_SQ     20172800ull
#define OFF_ABITS  20273664ull    // [25216][4] u64
#define OFF_DEG    21080576ull
#define OFF_FETHI  21181440ull    // [25280][768] bf16
#define OFF_MSGT   60011520ull    // [512][28672] bf16 = 29,360,128
#define OFF_H1     89371648ull    // [25216][1024] bf16
#define OFF_FETLO  OFF_MSGT       // overlay
#define OFF_POOL   141014016ull   // [128][2048] f32
#define OFF_P      142062592ull   // [128][512] f32
#define OFF_WC1    142324736ull   // [1024][768] bf16
#define OFF_WC2    143897600ull   // [1024][1024] bf16
#define OFF_G1     145994752ull   // [25216][200] f32, end 166,167,552

__device__ __forceinline__ void gll16(const void* g, void* l) {
  __builtin_amdgcn_global_load_lds((const __attribute__((address_space(1))) void*)g,
                                   (__attribute__((address_space(3))) void*)l, 16, 0, 0);
}

// Paired-row LDS layout for a 128row x 64B tile stored as [64][128B]:
// logical (row ar, 16B-chunk fch) lives at phys row (ar&63),
// slot ((ar>>6)*4 + fch) ^ ((ar&63)&7). Conflict-free (2-way) ds_read_b128.

// ---------------- all four weight casts in one launch ----------------
__global__ __launch_bounds__(256) void cast_weights(const float* __restrict__ w10,
                                                    const float* __restrict__ w20,
                                                    const float* __restrict__ w11,
                                                    const float* __restrict__ w21,
                                                    __hip_bfloat16* __restrict__ wc1,
                                                    __hip_bfloat16* __restrict__ wc2) {
  const int S1 = NH_ * F_ / 4;   // 98304
  const int S2 = NH_ * D2_ / 4;  // 131072
  int i = blockIdx.x * 256 + threadIdx.x;
  const float* src;
  __hip_bfloat16* dst;
  int off;
  if (i < S1) { src = w10; dst = wc1; off = i; }
  else if (i < 2 * S1) { src = w20; dst = wc1 + (size_t)NH_ * F_; off = i - S1; }
  else if (i < 2 * S1 + S2) { src = w11; dst = wc2; off = i - 2 * S1; }
  else { src = w21; dst = wc2 + (size_t)NH_ * D2_; off = i - 2 * S1 - S2; }
  float4 v = ((const float4*)src)[off];
  union { __hip_bfloat16 h[4]; uint2 u; } pk;
  pk.h[0] = __float2bfloat16(v.x);
  pk.h[1] = __float2bfloat16(v.y);
  pk.h[2] = __float2bfloat16(v.z);
  pk.h[3] = __float2bfloat16(v.w);
  ((uint2*)dst)[off] = pk.u;
}

// ---------------- f32 -> bf16 hi/lo split + squared norms (one Fet read) ----------------
__global__ __launch_bounds__(256) void cast_hilo_sq(const float* __restrict__ X,
                                                    __hip_bfloat16* __restrict__ hi,
                                                    __hip_bfloat16* __restrict__ lo,
                                                    float* __restrict__ sq) {
  int row = blockIdx.x * 4 + (threadIdx.x >> 6);
  int lane = threadIdx.x & 63;
  const float4* xp = (const float4*)(X + (size_t)row * F_);
  uint2* hp = (uint2*)(hi + (size_t)row * F_);
  uint2* lp = (uint2*)(lo + (size_t)row * F_);
  float s = 0.f;
#pragma unroll
  for (int i = 0; i < 3; i++) {
    float4 v = xp[lane + i * 64];
    s += v.x * v.x + v.y * v.y + v.z * v.z + v.w * v.w;
    float f[4] = {v.x, v.y, v.z, v.w};
    union { __hip_bfloat16 h[4]; uint2 u; } ph, pl;
#pragma unroll
    for (int k = 0; k < 4; k++) {
      __hip_bfloat16 h = __float2bfloat16(f[k]);
      ph.h[k] = h;
      pl.h[k] = __float2bfloat16(f[k] - __bfloat162float(h));
    }
    hp[lane + i * 64] = ph.u;
    lp[lane + i * 64] = pl.u;
  }
#pragma unroll
  for (int o = 32; o > 0; o >>= 1) s += __shfl_down(s, o);
  if (lane == 0) sq[row] = s;
}

// ---------------- pairwise Gram via MFMA, split-bf16 3-pass, K-split x2 (BK=32) -------
__global__ __launch_bounds__(256) void mfma_gram(const __hip_bfloat16* __restrict__ Xhi,
                                                 const __hip_bfloat16* __restrict__ Xlo,
                                                 float* __restrict__ g0,
                                                 float* __restrict__ g1) {
  __shared__ short AsH[4096];
  __shared__ short BsH[4096];
  __shared__ short AsL[4096];
  __shared__ short BsL[4096];
  const int t = threadIdx.x;
  const int wgid = blockIdx.x;
  const int L = (wgid & 7) * 96 + (wgid >> 3);
  const int b = L / 6;
  const int rbx = L - b * 6;
  const int bx = rbx % 3;
  const int khalf = rbx / 3;
  const int m0 = (bx == 0) ? 0 : 128;
  const int o0 = (bx == 2) ? 128 : 0;
  const bool mirror = (bx == 1);
  const int l = t & 63, w = t >> 6;
  const int wm = (w >> 1) * 64, wn = (w & 1) * 64;
  const int frow = l & 15, fch = l >> 4;
  const size_t rowbase = (size_t)b * N_;
  const char* AhiB = (const char*)(Xhi + (rowbase + m0) * F_);
  const char* AloB = (const char*)(Xlo + (rowbase + m0) * F_);
  const char* BhiB = (const char*)(Xhi + (rowbase + o0) * F_);
  const char* BloB = (const char*)(Xlo + (rowbase + o0) * F_);
  const int rb = F_ * 2;
  char* AsHB = (char*)AsH;
  char* BsHB = (char*)BsH;
  char* AsLB = (char*)AsL;
  char* BsLB = (char*)BsL;
  float* go = khalf ? g1 : g0;
  f32x4 zero = {0.f, 0.f, 0.f, 0.f};
  f32x4 acc[4][4];
#pragma unroll
  for (int i = 0; i < 4; i++)
#pragma unroll
    for (int j = 0; j < 4; j++) acc[i][j] = zero;
  const int kt0 = khalf * 12;
  for (int kt = kt0; kt < kt0 + 12; kt++) {
    const int kb = kt * 64;
#pragma unroll
    for (int u = 0; u < 2; u++) {
      int prow = u * 32 + (t >> 3);
      int e = (t & 7) ^ (prow & 7);
      int grow = (e >> 2) * 64 + prow;
      size_t goff = (size_t)grow * rb + kb + (e & 3) * 16;
      gll16(AhiB + goff, AsHB + u * 4096 + t * 16);
      gll16(BhiB + goff, BsHB + u * 4096 + t * 16);
      gll16(AloB + goff, AsLB + u * 4096 + t * 16);
      gll16(BloB + goff, BsLB + u * 4096 + t * 16);
    }
    __syncthreads();
    bf16x8 ah[4], al[4], bh[4], bl[4];
#pragma unroll
    for (int i = 0; i < 4; i++) {
      int ar = wm + i * 16 + frow;
      int apr = ar & 63;
      int aoff = apr * 128 + (((((ar >> 6) << 2) | fch) ^ (apr & 7)) * 16);
      ah[i] = *(const bf16x8*)(AsHB + aoff);
      al[i] = *(const bf16x8*)(AsLB + aoff);
      int br = wn + i * 16 + frow;
      int bpr = br & 63;
      int boff = bpr * 128 + (((((br >> 6) << 2) | fch) ^ (bpr & 7)) * 16);
      bh[i] = *(const bf16x8*)(BsHB + boff);
      bl[i] = *(const bf16x8*)(BsLB + boff);
    }
    // swapped: D col = A-tile row (n), D row = B-tile row (m)
#pragma unroll
    for (int i = 0; i < 4; i++)
#pragma unroll
      for (int j = 0; j < 4; j++) {
        acc[i][j] = __builtin_amdgcn_mfma_f32_16x16x32_bf16(bh[j], ah[i], acc[i][j], 0, 0, 0);
        acc[i][j] = __builtin_amdgcn_mfma_f32_16x16x32_bf16(bl[j], ah[i], acc[i][j], 0, 0, 0);
        acc[i][j] = __builtin_amdgcn_mfma_f32_16x16x32_bf16(bh[j], al[i], acc[i][j], 0, 0, 0);
      }
    __syncthreads();
  }
#pragma unroll
  for (int i = 0; i < 4; i++) {
    int n = m0 + wm + i * 16 + frow;
    if (n >= N_) continue;
    float* gr = go + (rowbase + n) * LDG_;
#pragma unroll
    for (int j = 0; j < 4; j++) {
      int mb = o0 + wn + j * 16 + fch * 4;
      if (mb >= LDG_) continue;
      f32x4 pv = acc[i][j];
      *(f32x4*)&gr[mb] = pv;
      if (mirror) {
#pragma unroll
        for (int r = 0; r < 4; r++)
          go[(rowbase + mb + r) * LDG_ + n] = pv[r];
      }
    }
  }
}

// ---------------- top-4 per row -> symmetric adjacency bitmask ----------------
__global__ __launch_bounds__(256) void topk_kernel(const float* __restrict__ g0,
                                                   const float* __restrict__ g1,
                                                   const float* __restrict__ sq,
                                                   unsigned long long* __restrict__ Abits) {
  int row = blockIdx.x * 4 + (threadIdx.x >> 6);
  int lane = threadIdx.x & 63;
  int b = row / N_, n = row - b * N_;
  const float* g0r = g0 + (size_t)row * LDG_;
  const float* g1r = g1 + (size_t)row * LDG_;
  const float* sqb = sq + (size_t)b * N_;
  float v[4];
  int vi[4];
#pragma unroll
  for (int i = 0; i < 4; i++) {
    int m = lane + i * 64;
    bool ok = (m < N_) && (m != n);
    v[i] = ok ? (sqb[m] - 2.f * (g0r[m] + g1r[m])) : INFINITY;
    vi[i] = ok ? m : 0x3fffffff;
  }
  unsigned long long nbr[4] = {0ull, 0ull, 0ull, 0ull};
#pragma unroll
  for (int t = 0; t < 4; t++) {
    float bv = v[0];
    int bi = vi[0];
#pragma unroll
    for (int i = 1; i < 4; i++)
      if (v[i] < bv || (v[i] == bv && vi[i] < bi)) { bv = v[i]; bi = vi[i]; }
#pragma unroll
    for (int o = 1; o < 64; o <<= 1) {
      float ov = __shfl_xor(bv, o);
      int oi = __shfl_xor(bi, o);
      if (ov < bv || (ov == bv && oi < bi)) { bv = ov; bi = oi; }
    }
#pragma unroll
    for (int i = 0; i < 4; i++)
      if (vi[i] == bi) { v[i] = INFINITY; vi[i] = 0x3fffffff; }
    if (lane == 0) {
      nbr[bi >> 6] |= 1ull << (bi & 63);
      atomicOr(&Abits[((size_t)b * N_ + bi) * 4 + (n >> 6)], 1ull << (n & 63));
    }
  }
  if (lane == 0) {
#pragma unroll
    for (int w = 0; w < 4; w++)
      if (nbr[w]) atomicOr(&Abits[(size_t)row * 4 + w], nbr[w]);
  }
}

// ---------------- 2-hop adjacency -> bf16 [B][256][224] (phase-shift b&3) + deg -------
__global__ __launch_bounds__(256) void a2_kernel(const unsigned long long* __restrict__ Abits,
                                                 __hip_bfloat16* __restrict__ A2bf,
                                                 float* __restrict__ deg) {
  int row = blockIdx.x * 4 + (threadIdx.x >> 6);
  int lane = threadIdx.x & 63;
  int b = row / N_, n = row - b * N_;
  const unsigned long long* arow = Abits + (size_t)row * 4;
  const unsigned long long* base = Abits + (size_t)b * N_ * 4;
  unsigned long long r0 = 0, r1 = 0, r2 = 0, r3 = 0;
#pragma unroll
  for (int w = 0; w < 4; w++) {
    if ((arow[w] >> lane) & 1ull) {
      const unsigned long long* mr = base + (size_t)(w * 64 + lane) * 4;
      r0 |= mr[0]; r1 |= mr[1]; r2 |= mr[2]; r3 |= mr[3];
    }
  }
#pragma unroll
  for (int o = 1; o < 64; o <<= 1) {
    r0 |= __shfl_xor(r0, o);
    r1 |= __shfl_xor(r1, o);
    r2 |= __shfl_xor(r2, o);
    r3 |= __shfl_xor(r3, o);
  }
  unsigned long long rr[4] = {r0, r1, r2, r3};
  rr[n >> 6] &= ~(1ull << (n & 63));
  const int pad = b & 3;
  __hip_bfloat16* out = A2bf + ((size_t)b * NA_ + n) * KA_;
  const __hip_bfloat16 one = __float2bfloat16(1.f);
  const __hip_bfloat16 zer = __float2bfloat16(0.f);
#pragma unroll
  for (int i = 0; i < 4; i++) {
    int m = lane + i * 64;
    if (m < KA_) {
      int k = m - pad;
      bool bit = (k >= 0 && k < N_ && ((rr[k >> 6] >> (k & 63)) & 1ull));
      out[m] = bit ? one : zer;
    }
  }
  if (lane == 0) {
    int dg = __popcll(rr[0]) + __popcll(rr[1]) + __popcll(rr[2]) + __popcll(rr[3]);
    deg[row] = (float)(dg > 0 ? dg : 1);
  }
}

// ---------------- merged ego+msg GEMM, BK=32, 2-phase dbuf prefetch pipeline ----------
// Stage for tile kt+1 is ISSUED before the ds_read+MFMA of tile kt; single barrier per
// K-step (compiler's vmcnt(0) drain then waits on loads issued a full phase earlier).
// LDS 32KB (2 x 16KB) is free: occupancy is VGPR-bound at 5 blocks/CU either way.
template <int MODE>
__global__ __launch_bounds__(256) void mfma_fused(const __hip_bfloat16* __restrict__ X,
                                                  const __hip_bfloat16* __restrict__ Wcat,
                                                  const float* __restrict__ biasE,
                                                  const float* __restrict__ biasM,
                                                  __hip_bfloat16* __restrict__ h1,
                                                  __hip_bfloat16* __restrict__ msgT,
                                                  float* __restrict__ pool,
                                                  int K) {
  __shared__ short As[2][4096];   // [buf][64 rows][128 B] paired-row layout
  __shared__ short Bs[2][4096];
  const int t = threadIdx.x;
  const int wgid = blockIdx.x;
  const int L = (wgid & 7) * 197 + (wgid >> 3);
  const int m0 = (L >> 3) * 128, o0 = (L & 7) * 128;
  const int l = t & 63, w = t >> 6;
  const int wm = (w >> 1) * 64, wn = (w & 1) * 64;
  const int frow = l & 15, fch = l >> 4;
  const char* Abase = (const char*)(X + (size_t)m0 * K);
  const char* Bbase = (const char*)(Wcat + (size_t)o0 * K);
  const int rb = K * 2;
  char* AsB = (char*)As;
  char* BsB = (char*)Bs;
  const bool ego = (o0 < 512);
  const bool swap = (MODE == 1) && ego;
  // per-thread staging invariants (paired-row inverse permutation)
  const int sp = t >> 3;
  const int se = (t & 7) ^ (sp & 7);
  const size_t goff0 = (size_t)((se >> 2) * 64 + sp) * rb + (se & 3) * 16;
  const size_t goff1 = (size_t)((se >> 2) * 64 + 32 + sp) * rb + (se & 3) * 16;
  auto stage = [&](int buf, int kt) {
    const int kb = kt * 64;
    const int d = buf * 8192 + t * 16;
    gll16(Abase + goff0 + kb, AsB + d);
    gll16(Abase + goff1 + kb, AsB + d + 4096);
    gll16(Bbase + goff0 + kb, BsB + d);
    gll16(Bbase + goff1 + kb, BsB + d + 4096);
  };
  f32x4 zero = {0.f, 0.f, 0.f, 0.f};
  f32x4 acc[4][4];
#pragma unroll
  for (int i = 0; i < 4; i++)
#pragma unroll
    for (int j = 0; j < 4; j++) acc[i][j] = zero;
  const int KT = K >> 5;
  stage(0, 0);
  __syncthreads();
  for (int kt = 0; kt < KT; kt++) {
    const int cur = kt & 1;
    if (kt + 1 < KT) stage(cur ^ 1, kt + 1);
    bf16x8 af[4], bfv[4];
#pragma unroll
    for (int i = 0; i < 4; i++) {
      int ar = wm + i * 16 + frow;
      int apr = ar & 63;
      af[i] = *(const bf16x8*)(AsB + cur * 8192 + apr * 128 +
                               (((((ar >> 6) << 2) | fch) ^ (apr & 7)) * 16));
      int br = wn + i * 16 + frow;
      int bpr = br & 63;
      bfv[i] = *(const bf16x8*)(BsB + cur * 8192 + bpr * 128 +
                                (((((br >> 6) << 2) | fch) ^ (bpr & 7)) * 16));
    }
    if (!swap) {
#pragma unroll
      for (int i = 0; i < 4; i++)
#pragma unroll
        for (int j = 0; j < 4; j++)
          acc[i][j] = __builtin_amdgcn_mfma_f32_16x16x32_bf16(af[i], bfv[j], acc[i][j], 0, 0, 0);
    } else {
#pragma unroll
      for (int i = 0; i < 4; i++)
#pragma unroll
        for (int j = 0; j < 4; j++)
          acc[i][j] = __builtin_amdgcn_mfma_f32_16x16x32_bf16(bfv[j], af[i], acc[i][j], 0, 0, 0);
    }
    __syncthreads();
  }
  if (ego) {
    if (MODE == 1) {
      // swapped: col(frow)=xrow, row(fch*4+r)=c -> packed uint2 + fused h1-ego pooling
      const int rw = m0 + wm;
      const int b0 = rw / N_;
      const int rloc = (b0 + 1) * N_ - rw;  // local batch boundary (may exceed 64)
#pragma unroll
      for (int j = 0; j < 4; j++) {
        int c0 = o0 + wn + j * 16 + fch * 4;
        float4 b4 = *(const float4*)&biasE[c0];
        float bb4[4] = {b4.x, b4.y, b4.z, b4.w};
        float sA4[4] = {0.f, 0.f, 0.f, 0.f};
        float sB4[4] = {0.f, 0.f, 0.f, 0.f};
#pragma unroll
        for (int i = 0; i < 4; i++) {
          int xloc = i * 16 + frow;
          union { __hip_bfloat16 h[4]; uint2 u; } pk;
#pragma unroll
          for (int r = 0; r < 4; r++) {
            float v = fmaxf(acc[i][j][r] + bb4[r], 0.f);
            pk.h[r] = __float2bfloat16(v);
            if (xloc < rloc) sA4[r] += v; else sB4[r] += v;
          }
          *(uint2*)&h1[(size_t)(rw + xloc) * D2_ + c0] = pk.u;
        }
#pragma unroll
        for (int r = 0; r < 4; r++) {
          float sA = sA4[r], sB = sB4[r];
          sA += __shfl_down(sA, 8, 16); sA += __shfl_down(sA, 4, 16);
          sA += __shfl_down(sA, 2, 16); sA += __shfl_down(sA, 1, 16);
          sB += __shfl_down(sB, 8, 16); sB += __shfl_down(sB, 4, 16);
          sB += __shfl_down(sB, 2, 16); sB += __shfl_down(sB, 1, 16);
          if ((l & 15) == 0) {
            atomicAdd(&pool[(size_t)b0 * D4_ + c0 + r], sA);
            if (rloc < 64) atomicAdd(&pool[(size_t)(b0 + 1) * D4_ + c0 + r], sB);
          }
        }
      }
    } else {
      // normal: col(frow)=c -> pool reduce (batch-boundary aware), offset D2_
#pragma unroll
      for (int j = 0; j < 4; j++) {
        int c = o0 + wn + j * 16 + frow;
        float bv = biasE[c];
        int rw = m0 + wm;
        int b0 = rw / N_;
        int rB = (b0 + 1) * N_;
        float sA = 0.f, sB = 0.f;
#pragma unroll
        for (int i = 0; i < 4; i++) {
          int r0 = m0 + wm + i * 16 + fch * 4;
#pragma unroll
          for (int r = 0; r < 4; r++) {
            float v = fmaxf(acc[i][j][r] + bv, 0.f);
            if (r0 + r < rB) sA += v; else sB += v;
          }
        }
        sA += __shfl_down(sA, 32);
        sA += __shfl_down(sA, 16);
        sB += __shfl_down(sB, 32);
        sB += __shfl_down(sB, 16);
        if (l < 16) {
          atomicAdd(&pool[(size_t)b0 * D4_ + D2_ + c], sA);
          if (rw + 64 > rB) atomicAdd(&pool[(size_t)(b0 + 1) * D4_ + D2_ + c], sB);
        }
      }
    }
  } else {
    // msg half, normal: col(frow)=cm, rows = xrow -> packed along rr
#pragma unroll
    for (int j = 0; j < 4; j++) {
      int cm = (o0 - 512) + wn + j * 16 + frow;
      float bm = biasM[cm];
      __hip_bfloat16* mrow = msgT + (size_t)cm * MT_LD_;
#pragma unroll
      for (int i = 0; i < 4; i++) {
        int x0 = m0 + wm + i * 16 + fch * 4;
        int b0 = x0 / N_;
        int r0 = x0 - b0 * N_;
        union { __hip_bfloat16 h[4]; uint2 u; } pk;
#pragma unroll
        for (int r = 0; r < 4; r++) pk.h[r] = __float2bfloat16(acc[i][j][r] + bm);
        if (r0 + 3 < N_) {
          *(uint2*)&mrow[b0 * KA_ + (b0 & 3) + r0] = pk.u;
        } else {
#pragma unroll
          for (int r = 0; r < 4; r++) {
            int x = x0 + r;
            int bb = x / N_;
            int rx = x - bb * N_;
            mrow[bb * KA_ + (bb & 3) + rx] = pk.h[r];
          }
        }
      }
    }
  }
}

// ---------------- MFMA aggregation: A2[b] @ msgT-slice, BK=32, dbuf, SWAPPED ----------
template <int MODE>
__global__ __launch_bounds__(256) void mfma_agg(const __hip_bfloat16* __restrict__ A2bf,
                                                const __hip_bfloat16* __restrict__ msgT,
                                                const float* __restrict__ deg,
                                                __hip_bfloat16* __restrict__ h1,
                                                float* __restrict__ pool, int poolOff) {
  __shared__ short As[2][4096];
  __shared__ short Bs[2][4096];
  const int t = threadIdx.x;
  const int wgid = blockIdx.x;
  const int L = (wgid & 7) * 128 + (wgid >> 3);
  const int b = L >> 3;
  const int o0 = ((L >> 1) & 3) * 128;
  const int m0 = (L & 1) * 128;
  const int l = t & 63, w = t >> 6;
  const int wm = (w >> 1) * 64, wn = (w & 1) * 64;
  const int frow = l & 15, fch = l >> 4;
  const char* Abase = (const char*)(A2bf + ((size_t)b * NA_ + m0) * KA_);
  const char* Bbase = (const char*)(msgT + (size_t)o0 * MT_LD_ + (size_t)b * KA_);
  char* AsB = (char*)As;
  char* BsB = (char*)Bs;
  const int sp = t >> 3;
  const int se = (t & 7) ^ (sp & 7);
  const int sg0 = (se >> 2) * 64 + sp;
  const int sg1 = sg0 + 32;
  const int sx = (se & 3) * 16;
  auto stage = [&](int buf, int kt) {
    const int kb = kt * 64;
    const int d = buf * 8192 + t * 16;
    gll16(Abase + (size_t)sg0 * (KA_ * 2) + kb + sx, AsB + d);
    gll16(Abase + (size_t)sg1 * (KA_ * 2) + kb + sx, AsB + d + 4096);
    gll16(Bbase + (size_t)sg0 * (MT_LD_ * 2) + kb + sx, BsB + d);
    gll16(Bbase + (size_t)sg1 * (MT_LD_ * 2) + kb + sx, BsB + d + 4096);
  };
  f32x4 zero = {0.f, 0.f, 0.f, 0.f};
  f32x4 acc[4][4];
#pragma unroll
  for (int i = 0; i < 4; i++)
#pragma unroll
    for (int j = 0; j < 4; j++) acc[i][j] = zero;
  stage(0, 0);
  __syncthreads();
  for (int kt = 0; kt < 7; kt++) {
    const int cur = kt & 1;
    if (kt + 1 < 7) stage(cur ^ 1, kt + 1);
    bf16x8 af[4], bfv[4];
#pragma unroll
    for (int i = 0; i < 4; i++) {
      int ar = wm + i * 16 + frow;
      int apr = ar & 63;
      af[i] = *(const bf16x8*)(AsB + cur * 8192 + apr * 128 +
                               (((((ar >> 6) << 2) | fch) ^ (apr & 7)) * 16));
      int br = wn + i * 16 + frow;
      int bpr = br & 63;
      bfv[i] = *(const bf16x8*)(BsB + cur * 8192 + bpr * 128 +
                                (((((br >> 6) << 2) | fch) ^ (bpr & 7)) * 16));
    }
    // swapped: D col(frow) = A2 row (n), D row(fch*4+r) = msgT row (c)
#pragma unroll
    for (int i = 0; i < 4; i++)
#pragma unroll
      for (int j = 0; j < 4; j++)
        acc[i][j] = __builtin_amdgcn_mfma_f32_16x16x32_bf16(bfv[j], af[i], acc[i][j], 0, 0, 0);
    __syncthreads();
  }
  float sv[4][4];
#pragma unroll
  for (int j = 0; j < 4; j++)
#pragma unroll
    for (int r = 0; r < 4; r++) sv[j][r] = 0.f;
#pragma unroll
  for (int i = 0; i < 4; i++) {
    int n = m0 + wm + i * 16 + frow;
    bool ok = (n < N_);
    float dinv = ok ? (1.f / deg[b * N_ + n]) : 0.f;
#pragma unroll
    for (int j = 0; j < 4; j++) {
      int c0 = o0 + wn + j * 16 + fch * 4;
      union { __hip_bfloat16 h[4]; uint2 u; } pk;
#pragma unroll
      for (int r = 0; r < 4; r++) {
        float v = ok ? fmaxf(acc[i][j][r] * dinv, 0.f) : 0.f;
        sv[j][r] += v;
        pk.h[r] = __float2bfloat16(v);
      }
      if (MODE == 0 && ok)
        *(uint2*)&h1[((size_t)b * N_ + n) * D2_ + NH_ + c0] = pk.u;
    }
  }
#pragma unroll
  for (int j = 0; j < 4; j++) {
#pragma unroll
    for (int r = 0; r < 4; r++) {
      float s = sv[j][r];
      s += __shfl_down(s, 8, 16);
      s += __shfl_down(s, 4, 16);
      s += __shfl_down(s, 2, 16);
      s += __shfl_down(s, 1, 16);
      if ((l & 15) == 0)
        atomicAdd(&pool[(size_t)b * D4_ + poolOff + o0 + wn + j * 16 + fch * 4 + r], s);
    }
  }
}

// ---------------- gf[:, 0:2048] = pool / N ----------------
__global__ __launch_bounds__(256) void scale_pool(const float* __restrict__ pool,
                                                  float* __restrict__ gf) {
  int b = blockIdx.y;
  int c = blockIdx.x * 256 + threadIdx.x;  // 0..2047
  gf[(size_t)b * D4_ + c] = pool[(size_t)b * D4_ + c] * (1.f / N_);
}

// ---------------- head GEMM: split-K f32, atomic accumulate ----------------
template <bool RELUX>
__global__ __launch_bounds__(256) void head_gemm(const float* __restrict__ Xg,
                                                 const float* __restrict__ W,
                                                 const float* __restrict__ bias,
                                                 float* __restrict__ Y,
                                                 int Rows, int Fin, int O, int kchunk) {
  __shared__ float Xs[16][68];
  __shared__ float Ws[16][68];
  int tx = threadIdx.x, ty = threadIdx.y;
  int tid = ty * 16 + tx;
  int lr = tid >> 2;
  int lk = (tid & 3) * 4;
  int rbase = blockIdx.y * 64;
  int o0 = blockIdx.x * 64;
  int k0base = blockIdx.z * kchunk;
  float acc[4][4] = {};
  for (int k0 = k0base; k0 < k0base + kchunk; k0 += 16) {
    float4 xv = make_float4(0.f, 0.f, 0.f, 0.f);
    if (rbase + lr < Rows) xv = *(const float4*)&Xg[(size_t)(rbase + lr) * Fin + k0 + lk];
    if (RELUX) {
      xv.x = fmaxf(xv.x, 0.f); xv.y = fmaxf(xv.y, 0.f);
      xv.z = fmaxf(xv.z, 0.f); xv.w = fmaxf(xv.w, 0.f);
    }
    Xs[lk][lr] = xv.x; Xs[lk + 1][lr] = xv.y; Xs[lk + 2][lr] = xv.z; Xs[lk + 3][lr] = xv.w;
    float4 wv = make_float4(0.f, 0.f, 0.f, 0.f);
    if (o0 + lr < O) wv = *(const float4*)&W[(size_t)(o0 + lr) * Fin + k0 + lk];
    Ws[lk][lr] = wv.x; Ws[lk + 1][lr] = wv.y; Ws[lk + 2][lr] = wv.z; Ws[lk + 3][lr] = wv.w;
    __syncthreads();
#pragma unroll
    for (int k = 0; k < 16; k++) {
      float4 a = *(const float4*)&Xs[k][ty * 4];
      float4 bb = *(const float4*)&Ws[k][tx * 4];
      float av[4] = {a.x, a.y, a.z, a.w};
      float bv[4] = {bb.x, bb.y, bb.z, bb.w};
#pragma unroll
      for (int i = 0; i < 4; i++)
#pragma unroll
        for (int j = 0; j < 4; j++) acc[i][j] = fmaf(av[i], bv[j], acc[i][j]);
    }
    __syncthreads();
  }
#pragma unroll
  for (int i = 0; i < 4; i++) {
    int rrow = rbase + ty * 4 + i;
    if (rrow >= Rows) continue;
#pragma unroll
    for (int j = 0; j < 4; j++) {
      int c = o0 + tx * 4 + j;
      if (c >= O) continue;
      float vv = acc[i][j] + ((blockIdx.z == 0) ? bias[c] : 0.f);
      atomicAdd(&Y[(size_t)rrow * O + c], vv);
    }
  }
}

// ---------------- host launch ----------------
extern "C" void kernel_launch(void* const* d_in, const int* in_sizes, int n_in,
                              void* d_out, int out_size, void* d_ws, size_t ws_size,
                              hipStream_t stream) {
  const float* Fet  = (const float*)d_in[0];
  const float* w1_0 = (const float*)d_in[1];
  const float* b1_0 = (const float*)d_in[2];
  const float* w2_0 = (const float*)d_in[3];
  const float* b2_0 = (const float*)d_in[4];
  const float* w1_1 = (const float*)d_in[5];
  const float* b1_1 = (const float*)d_in[6];
  const float* w2_1 = (const float*)d_in[7];
  const float* b2_1 = (const float*)d_in[8];
  const float* fc1_w = (const float*)d_in[9];
  const float* fc1_b = (const float*)d_in[10];
  const float* fc2_w = (const float*)d_in[11];
  const float* fc2_b = (const float*)d_in[12];

  char* ws = (char*)d_ws;
  float* g0 = (float*)(ws + OFF_G0);
  float* g1 = (float*)(ws + OFF_G1);
  __hip_bfloat16* A2bf = (__hip_bfloat16*)(ws + OFF_G0);  // overlay (g0 dead after topk)
  float* sq = (float*)(ws + OFF_SQ);
  unsigned long long* Abits = (unsigned long long*)(ws + OFF_ABITS);
  float* deg = (float*)(ws + OFF_DEG);
  __hip_bfloat16* Fet_hi = (__hip_bfloat16*)(ws + OFF_FETHI);
  __hip_bfloat16* Fet_lo = (__hip_bfloat16*)(ws + OFF_FETLO);  // overlay msgT/h1 head
  __hip_bfloat16* msgT = (__hip_bfloat16*)(ws + OFF_MSGT);
  __hip_bfloat16* h1 = (__hip_bfloat16*)(ws + OFF_H1);
  float* pool = (float*)(ws + OFF_POOL);
  float* p = (float*)(ws + OFF_P);
  __hip_bfloat16* wc1 = (__hip_bfloat16*)(ws + OFF_WC1);
  __hip_bfloat16* wc2 = (__hip_bfloat16*)(ws + OFF_WC2);

  float* out = (float*)d_out;          // [B, NC]
  float* gf = out + (size_t)B_ * NC_;  // [B, D4]

  hipMemsetAsync(Abits, 0, (size_t)ROWS_ * 4 * sizeof(unsigned long long), stream);
  hipMemsetAsync(pool, 0, (size_t)B_ * D4_ * sizeof(float), stream);
  hipMemsetAsync(p, 0, (size_t)B_ * NH_ * sizeof(float), stream);
  hipMemsetAsync(out, 0, (size_t)B_ * NC_ * sizeof(float), stream);

  // casts
  cast_hilo_sq<<<ROWS_ / 4, 256, 0, stream>>>(Fet, Fet_hi, Fet_lo, sq);
  cast_weights<<<1792, 256, 0, stream>>>(w1_0, w2_0, w1_1, w2_1, wc1, wc2);

  // graph construction
  mfma_gram<<<768, 256, 0, stream>>>(Fet_hi, Fet_lo, g0, g1);
  topk_kernel<<<ROWS_ / 4, 256, 0, stream>>>(g0, g1, sq, Abits);
  a2_kernel<<<ROWS_ / 4, 256, 0, stream>>>(Abits, A2bf, deg);

  // layer 1 (Fet_lo dead from here; msgT/h1 overwrite it). ego1 pool fused in-epilogue.
  mfma_fused<1><<<1576, 256, 0, stream>>>(Fet_hi, wc1, b1_0, b2_0, h1, msgT, pool, F_);
  mfma_agg<0><<<1024, 256, 0, stream>>>(A2bf, msgT, deg, h1, pool, NH_);

  // layer 2 (ego2 pooled in-epilogue; msg2 -> msgT -> agg2 pooled)
  mfma_fused<2><<<1576, 256, 0, stream>>>(h1, wc2, b1_1, b2_1, nullptr, msgT, pool, D2_);
  mfma_agg<1><<<1024, 256, 0, stream>>>(A2bf, msgT, deg, nullptr, pool, D2_ + NH_);

  // pooling -> graph_features (all 2048 cols from pool)
  scale_pool<<<dim3(8, B_), 256, 0, stream>>>(pool, gf);

  // head (f32, split-K + atomics; fc1 relu folded into fc2 X-load)
  head_gemm<false><<<dim3(8, 2, 16), dim3(16, 16), 0, stream>>>(
      gf, fc1_w, fc1_b, p, B_, D4_, NH_, 128);
  head_gemm<true><<<dim3(16, 2, 8), dim3(16, 16), 0, stream>>>(
      p, fc2_w, fc2_b, out, B_, NH_, NC_, 64);
}